// Round 14
// baseline (103.361 us; speedup 1.0000x reference)
//
#include <hip/hip_runtime.h>
#include <math.h>

#define BATCH 8
#define SEQ 2048
#define DIM 512
#define MTOT (BATCH*SEQ)
#define HID 30

typedef short bf16x8 __attribute__((ext_vector_type(8)));
typedef float f32x4 __attribute__((ext_vector_type(4)));

__device__ __forceinline__ unsigned short f2bf(float f) {
  unsigned int u = __float_as_uint(f);
  unsigned int r = (u + 0x7FFFu + ((u >> 16) & 1u)) >> 16;  // RNE
  return (unsigned short)r;
}
__device__ __forceinline__ float bf2f(unsigned short u) {
  return __uint_as_float((unsigned int)u << 16);
}

__device__ __forceinline__ void gload_lds16(const void* g, void* l) {
  __builtin_amdgcn_global_load_lds((const __attribute__((address_space(1))) void*)g,
                                   (__attribute__((address_space(3))) void*)l, 16, 0, 0);
}

// ---- 128x128 tile core: 4 waves (2x2), BK=32, 4-slot ring, counted vmcnt(8),
// 1 barrier/tile. (R12/R13-verified; acc = 64 VGPR -> fits a 128-reg clamp, so a
// 256-thread block can co-reside 2x per CU: LDS 64KB ring, ~116 VGPR.)
// Zero-conflict macro-row layout: row r = 8x16B chunks (A: ss0-3, B: ss4-7),
// physical slot = ss ^ (r&7); staged linearly via global_load_lds, pre-swizzled source.
__device__ __forceinline__ void gemm128_core(const unsigned short* __restrict__ gA,
                                             const unsigned short* __restrict__ gB,
                                             char* smem, f32x4 (&acc)[4][4]) {
  const int t = threadIdx.x;  // 0..255
  const int lane = t & 63;
  const int w = t >> 6;
  const int wr = w >> 1, wc = w & 1;
  const int lr = lane & 15, kc = lane >> 4;
  const int ss = (t & 7) ^ ((t >> 3) & 7);
  const unsigned short* gsrc = (ss < 4 ? gA : gB) + (size_t)(t >> 3) * DIM + (ss & 3) * 8;
  const uint32_t dbase = (uint32_t)(t & 192) * 16;

  auto stage = [&](int slot, int kt) {
#pragma unroll
    for (int q = 0; q < 4; ++q)
      gload_lds16(gsrc + (size_t)(q * 32) * DIM + kt * 32,
                  smem + slot * 16384 + q * 4096 + dbase);
  };

  stage(0, 0); stage(1, 1); stage(2, 2);
  asm volatile("s_waitcnt vmcnt(8)" ::: "memory");
  __builtin_amdgcn_s_barrier();
  asm volatile("" ::: "memory");

#pragma unroll
  for (int kt = 0; kt < 16; ++kt) {
    const char* Ab = smem + (kt & 3) * 16384;
    const int fslot = (kt + 3) & 3;
    const int src = (kt + 3 < 16) ? (kt + 3) : 15;
    bf16x8 bfr[4], af[4];
#pragma unroll
    for (int j = 0; j < 4; ++j) {
      int r = wc * 64 + j * 16 + lr;
      bfr[j] = *(const bf16x8*)(Ab + r * 128 + (((4 + kc) ^ (r & 7)) << 4));
    }
#pragma unroll
    for (int i = 0; i < 4; ++i) {
      int r = wr * 64 + i * 16 + lr;
      af[i] = *(const bf16x8*)(Ab + r * 128 + ((kc ^ (r & 7)) << 4));
    }
    __builtin_amdgcn_sched_barrier(0);
    stage(fslot, src);
    __builtin_amdgcn_sched_barrier(0);
    __builtin_amdgcn_s_setprio(1);
#pragma unroll
    for (int i = 0; i < 4; ++i)
#pragma unroll
      for (int j = 0; j < 4; ++j)
        acc[i][j] = __builtin_amdgcn_mfma_f32_16x16x32_bf16(af[i], bfr[j], acc[i][j], 0, 0, 0);
    __builtin_amdgcn_s_setprio(0);
    __builtin_amdgcn_sched_barrier(0);
    asm volatile("s_waitcnt vmcnt(8)" ::: "memory");
    __builtin_amdgcn_s_barrier();
    asm volatile("" ::: "memory");
  }
}

// ---- k_prep: 0-255 gmat 32x32 | 256-287 u | 288-319 wv2 | 320 consts | 321+ R->bf16 ----
__global__ __launch_bounds__(256) void k_prep(
    const float* __restrict__ R, const float* __restrict__ Wq, const float* __restrict__ Wk,
    const float* __restrict__ Wv, const float* __restrict__ bq, const float* __restrict__ bv,
    const float* __restrict__ W1, const float* __restrict__ b1,
    const float* __restrict__ W2, const float* __restrict__ b2,
    unsigned short* __restrict__ Gt, unsigned short* __restrict__ Rb16,
    float* __restrict__ u, float* __restrict__ wv2, float* __restrict__ consts) {
  __shared__ __align__(16) float As[16][34];
  __shared__ __align__(16) float Bs[16][34];
  __shared__ float vecs[512];
  __shared__ float red2[16][17];
  const int bid = blockIdx.x;
  const int t = threadIdx.x;

  if (bid >= 321) {  // R -> bf16 convert only
    size_t base = ((size_t)(bid - 321) * 256 + t) * 8;
    float4 r0 = *(const float4*)&R[base];
    float4 r1 = *(const float4*)&R[base + 4];
    ushort4 lo, hi;
    lo.x = f2bf(r0.x); lo.y = f2bf(r0.y); lo.z = f2bf(r0.z); lo.w = f2bf(r0.w);
    hi.x = f2bf(r1.x); hi.y = f2bf(r1.y); hi.z = f2bf(r1.z); hi.w = f2bf(r1.w);
    *(ushort4*)&Rb16[base] = lo;
    *(ushort4*)&Rb16[base + 4] = hi;
    return;
  }
  if (bid < 256) {  // Gt[q2][q1] = sum_d Wq[d][q1] Wk[d][q2], 32x32 tiles
    int tm = t & 15, tn = t >> 4;
    int q1b = (bid & 15) * 32, q2b = (bid >> 4) * 32;
    int lk = t >> 4, lc = (t & 15) * 2;
    float acc[2][2] = {};
    for (int kb = 0; kb < DIM; kb += 16) {
      *(float2*)&As[lk][lc] = *(const float2*)&Wq[(size_t)(kb + lk) * DIM + q1b + lc];
      *(float2*)&Bs[lk][lc] = *(const float2*)&Wk[(size_t)(kb + lk) * DIM + q2b + lc];
      __syncthreads();
#pragma unroll
      for (int k = 0; k < 16; ++k) {
        float a0 = As[k][tm * 2], a1 = As[k][tm * 2 + 1];
        float b0 = Bs[k][tn * 2], b1v = Bs[k][tn * 2 + 1];
        acc[0][0] = fmaf(a0, b0, acc[0][0]); acc[0][1] = fmaf(a0, b1v, acc[0][1]);
        acc[1][0] = fmaf(a1, b0, acc[1][0]); acc[1][1] = fmaf(a1, b1v, acc[1][1]);
      }
      __syncthreads();
    }
#pragma unroll
    for (int i = 0; i < 2; ++i)
#pragma unroll
      for (int j = 0; j < 2; ++j)
        Gt[(size_t)(q2b + tn * 2 + j) * DIM + (q1b + tm * 2 + i)] = f2bf(acc[i][j]);
    return;
  }
  if (bid < 320) {
    bool isU = bid < 288;
    int qb = (bid - (isU ? 256 : 288)) * 16;
    if (isU) {
      vecs[t] = bq[t];
      vecs[t + 256] = bq[t + 256];
    } else {
      for (int d = t; d < DIM; d += 256) {
        float s = 0.f;
        for (int j = 0; j < HID; ++j) s = fmaf(W2[j], W1[(size_t)j * DIM + d], s);
        vecs[d] = s;
      }
    }
    __syncthreads();
    const float* M = isU ? Wk : Wv;
    int ql = t & 15, ds = t >> 4;
    float s = 0.f;
#pragma unroll 8
    for (int i = 0; i < 32; ++i) {
      int d = ds * 32 + i;
      s = fmaf(vecs[d], M[(size_t)d * DIM + qb + ql], s);
    }
    red2[ds][ql] = s;
    __syncthreads();
    if (t < 16) {
      float r = 0.f;
#pragma unroll
      for (int k = 0; k < 16; ++k) r += red2[k][t];
      (isU ? u : wv2)[qb + t] = r;
    }
    return;
  }
  // bid == 320: const1 = bv.w12 ; c0 = W2.b1 + b2
  {
    for (int d = t; d < DIM; d += 256) {
      float s = 0.f;
      for (int j = 0; j < HID; ++j) s = fmaf(W2[j], W1[(size_t)j * DIM + d], s);
      vecs[d] = s;
    }
    __syncthreads();
    float* red = (float*)red2;
    red[t] = bv[t] * vecs[t] + bv[t + 256] * vecs[t + 256];
    __syncthreads();
    for (int o = 128; o > 0; o >>= 1) {
      if (t < o) red[t] += red[t + o];
      __syncthreads();
    }
    if (t == 0) {
      consts[0] = red[0];
      float s = b2[0];
      for (int j = 0; j < HID; ++j) s = fmaf(W2[j], b1[j], s);
      consts[1] = s;
    }
  }
}

// ---- k_projT: T = Rb16 @ Gt^T + u (128x128 core); blockIdx.y==0 also computes vw ----
__global__ __launch_bounds__(256, 4) void k_projT(const unsigned short* __restrict__ Rb16,
                                                  const unsigned short* __restrict__ Gt,
                                                  const float* __restrict__ u,
                                                  const float* __restrict__ wv2,
                                                  unsigned short* __restrict__ Tb16,
                                                  float* __restrict__ vw) {
  __shared__ __align__(16) char smem[65536];
  __shared__ float u_lds[128];
  int t = threadIdx.x;
  size_t rowb = (size_t)blockIdx.x * 128;
  int colb = blockIdx.y * 128;
  if (t < 128) u_lds[t] = u[colb + t];
  f32x4 acc[4][4] = {};
  gemm128_core(Rb16 + rowb * DIM, Gt + (size_t)colb * DIM, smem, acc);
  int lane = t & 63, w = t >> 6, wr = w >> 1, wc = w & 1;
  int lr = lane & 15, kq = lane >> 4;
#pragma unroll
  for (int i = 0; i < 4; ++i)
#pragma unroll
    for (int j = 0; j < 4; ++j)
#pragma unroll
      for (int r = 0; r < 4; ++r) {
        int row = wr * 64 + i * 16 + kq * 4 + r;
        int col = wc * 64 + j * 16 + lr;
        Tb16[(rowb + row) * DIM + colb + col] = f2bf(acc[i][j][r] + u_lds[col]);
      }
  if (blockIdx.y == 0) {  // vw[n] = Rb16[n].wv2 (const1 folded into k_final)
    float* wv2s = (float*)smem;
    __syncthreads();
    if (t < 256) { wv2s[t] = wv2[t]; wv2s[t + 256] = wv2[t + 256]; }
    __syncthreads();
    int row = (int)rowb + (t >> 1);
    const unsigned short* rp = Rb16 + (size_t)row * DIM + (t & 1) * 256;
    const float* wp = wv2s + (t & 1) * 256;
    float s = 0.f;
#pragma unroll 8
    for (int i = 0; i < 32; ++i) {
      bf16x8 v = *(const bf16x8*)(rp + i * 8);
#pragma unroll
      for (int e = 0; e < 8; ++e) s = fmaf(bf2f((unsigned short)v[e]), wp[i * 8 + e], s);
    }
    s += __shfl_xor(s, 1);
    if ((t & 1) == 0) vw[row] = s;
  }
}

// ---- k_qk: S = T @ R^T (128x128 core, 2 blocks/CU) + exp + fused s1/den partials ----
__global__ __launch_bounds__(256, 4) void k_qk(const unsigned short* __restrict__ Tb16,
                                               const unsigned short* __restrict__ Rb16,
                                               const float* __restrict__ vw,
                                               float* __restrict__ part_s1,
                                               float* __restrict__ part_den) {
  __shared__ __align__(16) char smem[65536];
  __shared__ float vw_lds[128];
  __shared__ float red_s1[2][128], red_den[2][128];
  int t = threadIdx.x;
  // XCD swizzle: 2048 blocks, 256 per XCD -> each XCD owns one batch (4MB panels, L2-fit)
  int orig = blockIdx.x;
  int wgid = (orig & 7) * 256 + (orig >> 3);
  int b = wgid >> 8;
  int nb = ((wgid >> 4) & 15) * 128;
  int mb = (wgid & 15) * 128;
  if (t < 128) vw_lds[t] = vw[b * SEQ + mb + t];
  f32x4 acc[4][4] = {};
  gemm128_core(Tb16 + ((size_t)b * SEQ + nb) * DIM,
               Rb16 + ((size_t)b * SEQ + mb) * DIM, smem, acc);
  int lane = t & 63, w = t >> 6, wr = w >> 1, wc = w & 1;
  int lr = lane & 15, kq = lane >> 4;
  const float rs = 0.044194173824159216f;  // 1/sqrt(512)
  float vwl[4];
#pragma unroll
  for (int j = 0; j < 4; ++j) vwl[j] = vw_lds[wc * 64 + j * 16 + lr];
#pragma unroll
  for (int i = 0; i < 4; ++i) {
#pragma unroll
    for (int r = 0; r < 4; ++r) {
      float sa = 0.f, sd = 0.f;
#pragma unroll
      for (int j = 0; j < 4; ++j) {
        float e = __expf(acc[i][j][r] * rs);
        sa = fmaf(e, vwl[j], sa);
        sd += e;
      }
#pragma unroll
      for (int m = 1; m < 16; m <<= 1) { sa += __shfl_xor(sa, m); sd += __shfl_xor(sd, m); }
      if (lr == 0) {
        int rl = wr * 64 + i * 16 + kq * 4 + r;
        red_s1[wc][rl] = sa;
        red_den[wc][rl] = sd;
      }
    }
  }
  __syncthreads();
  if (t < 128) {
    size_t o = ((size_t)b * 16 + (mb >> 7)) * SEQ + nb + t;
    part_s1[o] = red_s1[0][t] + red_s1[1][t];
    part_den[o] = red_den[0][t] + red_den[1][t];
  }
}

// ---- k_final: winner = s1/den + const1 + c0 ----
__global__ void k_final(const float* __restrict__ part_s1, const float* __restrict__ part_den,
                        const float* __restrict__ consts, float* __restrict__ out) {
  int n = blockIdx.x * 256 + threadIdx.x;
  int b = n >> 11, nn = n & 2047;
  float s1 = 0.f, dn = 0.f;
#pragma unroll
  for (int i = 0; i < 16; ++i) {
    size_t o = ((size_t)b * 16 + i) * SEQ + nn;
    s1 += part_s1[o];
    dn += part_den[o];
  }
  out[n] = s1 / dn + consts[0] + consts[1];
}

extern "C" void kernel_launch(void* const* d_in, const int* in_sizes, int n_in,
                              void* d_out, int out_size, void* d_ws, size_t ws_size,
                              hipStream_t stream) {
  const float* R  = (const float*)d_in[0];
  const float* Wq = (const float*)d_in[1];
  const float* bq = (const float*)d_in[2];
  const float* Wk = (const float*)d_in[3];
  const float* bk = (const float*)d_in[4];  // cancels in row-softmax
  const float* Wv = (const float*)d_in[5];
  const float* bv = (const float*)d_in[6];
  const float* W1 = (const float*)d_in[7];
  const float* b1 = (const float*)d_in[8];
  const float* W2 = (const float*)d_in[9];
  const float* b2 = (const float*)d_in[10];
  (void)bk;
  float* out = (float*)d_out;

  char* p = (char*)d_ws;
  unsigned short* Rb16 = (unsigned short*)p; p += (size_t)MTOT * DIM * 2;
  unsigned short* Tb16 = (unsigned short*)p; p += (size_t)MTOT * DIM * 2;
  unsigned short* Gt   = (unsigned short*)p; p += (size_t)DIM * DIM * 2;
  float* part_s1  = (float*)p; p += (size_t)BATCH * 16 * SEQ * 4;
  float* part_den = (float*)p; p += (size_t)BATCH * 16 * SEQ * 4;
  float* u      = (float*)p; p += DIM * 4;
  float* wv2    = (float*)p; p += DIM * 4;
  float* vw     = (float*)p; p += MTOT * 4;
  float* consts = (float*)p; p += 16;

  hipLaunchKernelGGL(k_prep, dim3(321 + MTOT * DIM / (256 * 8)), dim3(256), 0, stream,
                     R, Wq, Wk, Wv, bq, bv, W1, b1, W2, b2, Gt, Rb16, u, wv2, consts);
  hipLaunchKernelGGL(k_projT, dim3(MTOT / 128, DIM / 128), dim3(256), 0, stream,
                     Rb16, Gt, u, wv2, Tb16, vw);
  hipLaunchKernelGGL(k_qk, dim3(2048), dim3(256), 0, stream, Tb16, Rb16, vw, part_s1, part_den);
  hipLaunchKernelGGL(k_final, dim3(MTOT / 256), dim3(256), 0, stream,
                     part_s1, part_den, consts, out);
}

// Round 15
// 98.214 us; speedup vs baseline: 1.0524x; 1.0524x over previous
//
#include <hip/hip_runtime.h>
#include <math.h>

#define BATCH 8
#define SEQ 2048
#define DIM 512
#define MTOT (BATCH*SEQ)
#define HID 30

typedef short bf16x8 __attribute__((ext_vector_type(8)));
typedef float f32x4 __attribute__((ext_vector_type(4)));

__device__ __forceinline__ unsigned short f2bf(float f) {
  unsigned int u = __float_as_uint(f);
  unsigned int r = (u + 0x7FFFu + ((u >> 16) & 1u)) >> 16;  // RNE
  return (unsigned short)r;
}
__device__ __forceinline__ float bf2f(unsigned short u) {
  return __uint_as_float((unsigned int)u << 16);
}

__device__ __forceinline__ void gload_lds16(const void* g, void* l) {
  __builtin_amdgcn_global_load_lds((const __attribute__((address_space(1))) void*)g,
                                   (__attribute__((address_space(3))) void*)l, 16, 0, 0);
}

// ---- 256x256 tile GEMM core (R8-verified BEST: k_qk 46.8us): C = A * B^T.
// BK=32, 8 waves (2x4), 3-slot LDS ring, counted vmcnt(4), ONE barrier per K-tile.
// Zero-conflict macro-row layout: row r = 8x16B chunks (A: ss0-3, B: ss4-7),
// physical slot = ss ^ (r&7); staged linearly via global_load_lds, pre-swizzled source.
__device__ __forceinline__ void gemm256_core(const unsigned short* __restrict__ gA,
                                             const unsigned short* __restrict__ gB,
                                             char* smem, f32x4 (&acc)[8][4]) {
  const int t = threadIdx.x;
  const int lane = t & 63;
  const int w = t >> 6;
  const int wr = w >> 2, wc = w & 3;
  const int lr = lane & 15, kc = lane >> 4;
  const int ss = (t & 7) ^ ((t >> 3) & 7);
  const unsigned short* gsrc = (ss < 4 ? gA : gB) + (size_t)(t >> 3) * DIM + (ss & 3) * 8;
  const uint32_t dbase = (uint32_t)(t & 448) * 16;  // wave-uniform base; HW adds lane*16

  auto stage = [&](int slot, int kt) {
#pragma unroll
    for (int q = 0; q < 4; ++q)
      gload_lds16(gsrc + (size_t)(q * 64) * DIM + kt * 32,
                  smem + slot * 32768 + q * 8192 + dbase);
  };

  stage(0, 0); stage(1, 1);
  asm volatile("s_waitcnt vmcnt(4)" ::: "memory");
  __builtin_amdgcn_s_barrier();
  asm volatile("" ::: "memory");

#pragma unroll
  for (int kt = 0; kt < 16; ++kt) {
    const char* Ab = smem + (kt % 3) * 32768;
    const int fslot = (kt + 2) % 3;
    const int src = (kt + 2 < 16) ? (kt + 2) : 15;  // dummy tail keeps vmcnt uniform
    bf16x8 bfr[4], af[4], af2[4];
#pragma unroll
    for (int j = 0; j < 4; ++j) {
      int r = wc * 64 + j * 16 + lr;
      bfr[j] = *(const bf16x8*)(Ab + r * 128 + (((4 + kc) ^ (r & 7)) << 4));
    }
#pragma unroll
    for (int i = 0; i < 4; ++i) {
      int r = wr * 128 + i * 16 + lr;
      af[i] = *(const bf16x8*)(Ab + r * 128 + ((kc ^ (r & 7)) << 4));
    }
    __builtin_amdgcn_sched_barrier(0);
#pragma unroll
    for (int i = 0; i < 4; ++i) {
      int r = wr * 128 + (i + 4) * 16 + lr;
      af2[i] = *(const bf16x8*)(Ab + r * 128 + ((kc ^ (r & 7)) << 4));
    }
    __builtin_amdgcn_sched_barrier(0);
    stage(fslot, src);
    __builtin_amdgcn_sched_barrier(0);
    __builtin_amdgcn_s_setprio(1);
#pragma unroll
    for (int i = 0; i < 4; ++i)   // compiler emits lgkmcnt(4): af2 still in flight
#pragma unroll
      for (int j = 0; j < 4; ++j)
        acc[i][j] = __builtin_amdgcn_mfma_f32_16x16x32_bf16(af[i], bfr[j], acc[i][j], 0, 0, 0);
    __builtin_amdgcn_s_setprio(0);
    __builtin_amdgcn_sched_barrier(0);
    __builtin_amdgcn_s_setprio(1);
#pragma unroll
    for (int i = 0; i < 4; ++i)   // compiler emits lgkmcnt(0)
#pragma unroll
      for (int j = 0; j < 4; ++j)
        acc[i + 4][j] = __builtin_amdgcn_mfma_f32_16x16x32_bf16(af2[i], bfr[j], acc[i + 4][j], 0, 0, 0);
    __builtin_amdgcn_s_setprio(0);
    __builtin_amdgcn_sched_barrier(0);
    asm volatile("s_waitcnt vmcnt(4)" ::: "memory");
    __builtin_amdgcn_s_barrier();
    asm volatile("" ::: "memory");
  }
}

// ---- 256x128 tile core for projT: 8 waves (4 row x 2 col), BK=64, 2-slot ring.
// Grid covers all 256 CUs in ONE round (64 x 4 blocks). Same verified geometry:
// A region 256 rows x 128B, B region 128 rows x 128B per slot (48KB/slot);
// macro-row = 8x16B chunks of one K-tile, physical chunk = ss ^ (row&7);
// staged linearly (dest = region + q*8192 + t*16), pre-swizzled per-lane source.
// stage(kt+1) at tile top; end-of-tile vmcnt(0) retires loads issued a full tile ago.
__device__ __forceinline__ void gemm256x128_core(const unsigned short* __restrict__ gA,
                                                 const unsigned short* __restrict__ gB,
                                                 char* smem, f32x4 (&acc)[4][4]) {
  const int t = threadIdx.x;  // 0..511
  const int lane = t & 63;
  const int w = t >> 6;
  const int wr = w >> 1, wc = w & 1;  // 4 row-waves x 2 col-waves
  const int lr = lane & 15, kc = lane >> 4;
  const int ss = (t & 7) ^ ((t >> 3) & 7);
  const size_t srcoff = (size_t)(t >> 3) * DIM + ss * 8;
  const uint32_t dbase = (uint32_t)(t & 448) * 16;

  auto stage = [&](int kt) {
    char* slot = smem + (kt & 1) * 49152;
#pragma unroll
    for (int q = 0; q < 4; ++q)  // A: rows (t>>3)+64q, q=0..3
      gload_lds16(gA + srcoff + (size_t)(q * 64) * DIM + kt * 64, slot + q * 8192 + dbase);
#pragma unroll
    for (int q = 0; q < 2; ++q)  // B: rows (t>>3)+64q, q=0..1
      gload_lds16(gB + srcoff + (size_t)(q * 64) * DIM + kt * 64, slot + 32768 + q * 8192 + dbase);
  };

  stage(0);
  asm volatile("s_waitcnt vmcnt(0)" ::: "memory");
  __builtin_amdgcn_s_barrier();
  asm volatile("" ::: "memory");

#pragma unroll
  for (int kt = 0; kt < 8; ++kt) {
    const char* Ab = smem + (kt & 1) * 49152;
    const char* Bb = Ab + 32768;
    if (kt < 7) stage(kt + 1);
    __builtin_amdgcn_sched_barrier(0);
#pragma unroll
    for (int s = 0; s < 2; ++s) {  // kstep: k-half of the 64-K tile
      bf16x8 bfr[4], af[4];
      const int ch = s * 4 + kc;   // chunk 0..7
#pragma unroll
      for (int j = 0; j < 4; ++j) {
        int r = wc * 64 + j * 16 + lr;   // 0..127
        bfr[j] = *(const bf16x8*)(Bb + r * 128 + ((ch ^ (r & 7)) << 4));
      }
#pragma unroll
      for (int i = 0; i < 4; ++i) {
        int r = wr * 64 + i * 16 + lr;   // 0..255
        af[i] = *(const bf16x8*)(Ab + r * 128 + ((ch ^ (r & 7)) << 4));
      }
      __builtin_amdgcn_sched_barrier(0);
      __builtin_amdgcn_s_setprio(1);
#pragma unroll
      for (int i = 0; i < 4; ++i)
#pragma unroll
        for (int j = 0; j < 4; ++j)
          acc[i][j] = __builtin_amdgcn_mfma_f32_16x16x32_bf16(af[i], bfr[j], acc[i][j], 0, 0, 0);
      __builtin_amdgcn_s_setprio(0);
      __builtin_amdgcn_sched_barrier(0);
    }
    asm volatile("s_waitcnt vmcnt(0)" ::: "memory");
    __builtin_amdgcn_s_barrier();
    asm volatile("" ::: "memory");
  }
}

// ---- k_prep: 0-255 gmat 32x32 | 256-287 u | 288-319 wv2 | 320 consts | 321+ R->bf16 ----
__global__ __launch_bounds__(256) void k_prep(
    const float* __restrict__ R, const float* __restrict__ Wq, const float* __restrict__ Wk,
    const float* __restrict__ Wv, const float* __restrict__ bq, const float* __restrict__ bv,
    const float* __restrict__ W1, const float* __restrict__ b1,
    const float* __restrict__ W2, const float* __restrict__ b2,
    unsigned short* __restrict__ Gt, unsigned short* __restrict__ Rb16,
    float* __restrict__ u, float* __restrict__ wv2, float* __restrict__ consts) {
  __shared__ __align__(16) float As[16][34];
  __shared__ __align__(16) float Bs[16][34];
  __shared__ float vecs[512];
  __shared__ float red2[16][17];
  const int bid = blockIdx.x;
  const int t = threadIdx.x;

  if (bid >= 321) {  // R -> bf16 convert only
    size_t base = ((size_t)(bid - 321) * 256 + t) * 8;
    float4 r0 = *(const float4*)&R[base];
    float4 r1 = *(const float4*)&R[base + 4];
    ushort4 lo, hi;
    lo.x = f2bf(r0.x); lo.y = f2bf(r0.y); lo.z = f2bf(r0.z); lo.w = f2bf(r0.w);
    hi.x = f2bf(r1.x); hi.y = f2bf(r1.y); hi.z = f2bf(r1.z); hi.w = f2bf(r1.w);
    *(ushort4*)&Rb16[base] = lo;
    *(ushort4*)&Rb16[base + 4] = hi;
    return;
  }
  if (bid < 256) {  // Gt[q2][q1] = sum_d Wq[d][q1] Wk[d][q2], 32x32 tiles
    int tm = t & 15, tn = t >> 4;
    int q1b = (bid & 15) * 32, q2b = (bid >> 4) * 32;
    int lk = t >> 4, lc = (t & 15) * 2;
    float acc[2][2] = {};
    for (int kb = 0; kb < DIM; kb += 16) {
      *(float2*)&As[lk][lc] = *(const float2*)&Wq[(size_t)(kb + lk) * DIM + q1b + lc];
      *(float2*)&Bs[lk][lc] = *(const float2*)&Wk[(size_t)(kb + lk) * DIM + q2b + lc];
      __syncthreads();
#pragma unroll
      for (int k = 0; k < 16; ++k) {
        float a0 = As[k][tm * 2], a1 = As[k][tm * 2 + 1];
        float b0 = Bs[k][tn * 2], b1v = Bs[k][tn * 2 + 1];
        acc[0][0] = fmaf(a0, b0, acc[0][0]); acc[0][1] = fmaf(a0, b1v, acc[0][1]);
        acc[1][0] = fmaf(a1, b0, acc[1][0]); acc[1][1] = fmaf(a1, b1v, acc[1][1]);
      }
      __syncthreads();
    }
#pragma unroll
    for (int i = 0; i < 2; ++i)
#pragma unroll
      for (int j = 0; j < 2; ++j)
        Gt[(size_t)(q2b + tn * 2 + j) * DIM + (q1b + tm * 2 + i)] = f2bf(acc[i][j]);
    return;
  }
  if (bid < 320) {
    bool isU = bid < 288;
    int qb = (bid - (isU ? 256 : 288)) * 16;
    if (isU) {
      vecs[t] = bq[t];
      vecs[t + 256] = bq[t + 256];
    } else {
      for (int d = t; d < DIM; d += 256) {
        float s = 0.f;
        for (int j = 0; j < HID; ++j) s = fmaf(W2[j], W1[(size_t)j * DIM + d], s);
        vecs[d] = s;
      }
    }
    __syncthreads();
    const float* M = isU ? Wk : Wv;
    int ql = t & 15, ds = t >> 4;
    float s = 0.f;
#pragma unroll 8
    for (int i = 0; i < 32; ++i) {
      int d = ds * 32 + i;
      s = fmaf(vecs[d], M[(size_t)d * DIM + qb + ql], s);
    }
    red2[ds][ql] = s;
    __syncthreads();
    if (t < 16) {
      float r = 0.f;
#pragma unroll
      for (int k = 0; k < 16; ++k) r += red2[k][t];
      (isU ? u : wv2)[qb + t] = r;
    }
    return;
  }
  // bid == 320: const1 = bv.w12 ; c0 = W2.b1 + b2
  {
    for (int d = t; d < DIM; d += 256) {
      float s = 0.f;
      for (int j = 0; j < HID; ++j) s = fmaf(W2[j], W1[(size_t)j * DIM + d], s);
      vecs[d] = s;
    }
    __syncthreads();
    float* red = (float*)red2;
    red[t] = bv[t] * vecs[t] + bv[t + 256] * vecs[t + 256];
    __syncthreads();
    for (int o = 128; o > 0; o >>= 1) {
      if (t < o) red[t] += red[t + o];
      __syncthreads();
    }
    if (t == 0) {
      consts[0] = red[0];
      float s = b2[0];
      for (int j = 0; j < HID; ++j) s = fmaf(W2[j], b1[j], s);
      consts[1] = s;
    }
  }
}

// ---- k_projT: T = Rb16 @ Gt^T + u (256x128 core, 256 blocks = 1/CU);
//      blockIdx.y==0 blocks also compute vw ----
__global__ __launch_bounds__(512, 2) void k_projT(const unsigned short* __restrict__ Rb16,
                                                  const unsigned short* __restrict__ Gt,
                                                  const float* __restrict__ u,
                                                  const float* __restrict__ wv2,
                                                  unsigned short* __restrict__ Tb16,
                                                  float* __restrict__ vw) {
  __shared__ __align__(16) char smem[98304];  // 2 slots x (A 32KB + B 16KB)
  __shared__ float u_lds[128];
  int t = threadIdx.x;
  size_t rowb = (size_t)blockIdx.x * 256;
  int colb = blockIdx.y * 128;
  if (t < 128) u_lds[t] = u[colb + t];
  f32x4 acc[4][4] = {};
  gemm256x128_core(Rb16 + rowb * DIM, Gt + (size_t)colb * DIM, smem, acc);
  int lane = t & 63, w = t >> 6, wr = w >> 1, wc = w & 1;
  int lr = lane & 15, kq = lane >> 4;
#pragma unroll
  for (int i = 0; i < 4; ++i)
#pragma unroll
    for (int j = 0; j < 4; ++j)
#pragma unroll
      for (int r = 0; r < 4; ++r) {
        int row = wr * 64 + i * 16 + kq * 4 + r;
        int col = wc * 64 + j * 16 + lr;
        Tb16[(rowb + row) * DIM + colb + col] = f2bf(acc[i][j][r] + u_lds[col]);
      }
  if (blockIdx.y == 0) {  // vw[n] = Rb16[n].wv2 (const1 folded into k_final)
    // safe: no loads in flight at core exit (no dummy tail; final vmcnt(0) retired all)
    float* wv2s = (float*)smem;
    __syncthreads();
    if (t < 512) { wv2s[t] = wv2[t]; }
    __syncthreads();
    int row = (int)rowb + (t >> 1);
    const unsigned short* rp = Rb16 + (size_t)row * DIM + (t & 1) * 256;
    const float* wp = wv2s + (t & 1) * 256;
    float s = 0.f;
#pragma unroll 8
    for (int i = 0; i < 32; ++i) {
      bf16x8 v = *(const bf16x8*)(rp + i * 8);
#pragma unroll
      for (int e = 0; e < 8; ++e) s = fmaf(bf2f((unsigned short)v[e]), wp[i * 8 + e], s);
    }
    s += __shfl_xor(s, 1);
    if ((t & 1) == 0) vw[row] = s;
  }
}

// ---- k_qk: S = T @ R^T (256x256 R8 core) + exp + fused s1/den partials ----
__global__ __launch_bounds__(512, 2) void k_qk(const unsigned short* __restrict__ Tb16,
                                               const unsigned short* __restrict__ Rb16,
                                               const float* __restrict__ vw,
                                               float* __restrict__ part_s1,
                                               float* __restrict__ part_den) {
  __shared__ __align__(16) char smem[98304];
  __shared__ float vw_lds[256];
  __shared__ float red_s1[4][256], red_den[4][256];
  int t = threadIdx.x;
  // XCD swizzle: each XCD owns one batch (T+R panels fit its 4MB L2)
  int orig = blockIdx.x;
  int wgid = (orig & 7) * 64 + (orig >> 3);
  int b = wgid >> 6;
  int nb = ((wgid >> 3) & 7) * 256;
  int mb = (wgid & 7) * 256;
  if (t < 256) vw_lds[t] = vw[b * SEQ + mb + t];
  f32x4 acc[8][4] = {};
  gemm256_core(Tb16 + ((size_t)b * SEQ + nb) * DIM,
               Rb16 + ((size_t)b * SEQ + mb) * DIM, smem, acc);
  int lane = t & 63, w = t >> 6, wr = w >> 2, wc = w & 3;
  int lr = lane & 15, kq = lane >> 4;
  const float rs = 0.044194173824159216f;  // 1/sqrt(512)
  float vwl[4];
#pragma unroll
  for (int j = 0; j < 4; ++j) vwl[j] = vw_lds[wc * 64 + j * 16 + lr];
#pragma unroll
  for (int i = 0; i < 8; ++i) {
#pragma unroll
    for (int r = 0; r < 4; ++r) {
      float sa = 0.f, sd = 0.f;
#pragma unroll
      for (int j = 0; j < 4; ++j) {
        float e = __expf(acc[i][j][r] * rs);
        sa = fmaf(e, vwl[j], sa);
        sd += e;
      }
#pragma unroll
      for (int m = 1; m < 16; m <<= 1) { sa += __shfl_xor(sa, m); sd += __shfl_xor(sd, m); }
      if (lr == 0) {
        int rl = wr * 128 + i * 16 + kq * 4 + r;
        red_s1[wc][rl] = sa;
        red_den[wc][rl] = sd;
      }
    }
  }
  __syncthreads();
  if (t < 256) {
    size_t o = ((size_t)b * 8 + (mb >> 8)) * SEQ + nb + t;
    part_s1[o] = red_s1[0][t] + red_s1[1][t] + red_s1[2][t] + red_s1[3][t];
    part_den[o] = red_den[0][t] + red_den[1][t] + red_den[2][t] + red_den[3][t];
  }
}

// ---- k_final: winner = s1/den + const1 + c0 ----
__global__ void k_final(const float* __restrict__ part_s1, const float* __restrict__ part_den,
                        const float* __restrict__ consts, float* __restrict__ out) {
  int n = blockIdx.x * 256 + threadIdx.x;
  int b = n >> 11, nn = n & 2047;
  float s1 = 0.f, dn = 0.f;
#pragma unroll
  for (int i = 0; i < 8; ++i) {
    size_t o = ((size_t)b * 8 + i) * SEQ + nn;
    s1 += part_s1[o];
    dn += part_den[o];
  }
  out[n] = s1 / dn + consts[0] + consts[1];
}

extern "C" void kernel_launch(void* const* d_in, const int* in_sizes, int n_in,
                              void* d_out, int out_size, void* d_ws, size_t ws_size,
                              hipStream_t stream) {
  const float* R  = (const float*)d_in[0];
  const float* Wq = (const float*)d_in[1];
  const float* bq = (const float*)d_in[2];
  const float* Wk = (const float*)d_in[3];
  const float* bk = (const float*)d_in[4];  // cancels in row-softmax
  const float* Wv = (const float*)d_in[5];
  const float* bv = (const float*)d_in[6];
  const float* W1 = (const float*)d_in[7];
  const float* b1 = (const float*)d_in[8];
  const float* W2 = (const float*)d_in[9];
  const float* b2 = (const float*)d_in[10];
  (void)bk;
  float* out = (float*)d_out;

  char* p = (char*)d_ws;
  unsigned short* Rb16 = (unsigned short*)p; p += (size_t)MTOT * DIM * 2;
  unsigned short* Tb16 = (unsigned short*)p; p += (size_t)MTOT * DIM * 2;
  unsigned short* Gt   = (unsigned short*)p; p += (size_t)DIM * DIM * 2;
  float* part_s1  = (float*)p; p += (size_t)BATCH * 8 * SEQ * 4;
  float* part_den = (float*)p; p += (size_t)BATCH * 8 * SEQ * 4;
  float* u      = (float*)p; p += DIM * 4;
  float* wv2    = (float*)p; p += DIM * 4;
  float* vw     = (float*)p; p += MTOT * 4;
  float* consts = (float*)p; p += 16;

  hipLaunchKernelGGL(k_prep, dim3(321 + MTOT * DIM / (256 * 8)), dim3(256), 0, stream,
                     R, Wq, Wk, Wv, bq, bv, W1, b1, W2, b2, Gt, Rb16, u, wv2, consts);
  hipLaunchKernelGGL(k_projT, dim3(MTOT / 256, DIM / 128), dim3(512), 0, stream,
                     Rb16, Gt, u, wv2, Tb16, vw);
  hipLaunchKernelGGL(k_qk, dim3(512), dim3(512), 0, stream, Tb16, Rb16, vw, part_s1, part_den);
  hipLaunchKernelGGL(k_final, dim3(MTOT / 256), dim3(256), 0, stream,
                     part_s1, part_den, consts, out);
}

// Round 16
// 95.729 us; speedup vs baseline: 1.0797x; 1.0260x over previous
//
#include <hip/hip_runtime.h>
#include <math.h>

#define BATCH 8
#define SEQ 2048
#define DIM 512
#define MTOT (BATCH*SEQ)
#define HID 30

typedef short bf16x8 __attribute__((ext_vector_type(8)));
typedef unsigned short u16x8 __attribute__((ext_vector_type(8)));
typedef float f32x4 __attribute__((ext_vector_type(4)));

__device__ __forceinline__ unsigned short f2bf(float f) {
  unsigned int u = __float_as_uint(f);
  unsigned int r = (u + 0x7FFFu + ((u >> 16) & 1u)) >> 16;  // RNE
  return (unsigned short)r;
}
__device__ __forceinline__ float bf2f(unsigned short u) {
  return __uint_as_float((unsigned int)u << 16);
}

__device__ __forceinline__ void gload_lds16(const void* g, void* l) {
  __builtin_amdgcn_global_load_lds((const __attribute__((address_space(1))) void*)g,
                                   (__attribute__((address_space(3))) void*)l, 16, 0, 0);
}

// ---- 256x256 tile GEMM core (R8-verified BEST: k_qk 46.8us): C = A * B^T.
// BK=32, 8 waves (2x4), 3-slot LDS ring, counted vmcnt(4), ONE barrier per K-tile.
// Zero-conflict macro-row layout: row r = 8x16B chunks (A: ss0-3, B: ss4-7),
// physical slot = ss ^ (r&7); staged linearly via global_load_lds, pre-swizzled source.
__device__ __forceinline__ void gemm256_core(const unsigned short* __restrict__ gA,
                                             const unsigned short* __restrict__ gB,
                                             char* smem, f32x4 (&acc)[8][4]) {
  const int t = threadIdx.x;
  const int lane = t & 63;
  const int w = t >> 6;
  const int wr = w >> 2, wc = w & 3;
  const int lr = lane & 15, kc = lane >> 4;
  const int ss = (t & 7) ^ ((t >> 3) & 7);
  const unsigned short* gsrc = (ss < 4 ? gA : gB) + (size_t)(t >> 3) * DIM + (ss & 3) * 8;
  const uint32_t dbase = (uint32_t)(t & 448) * 16;  // wave-uniform base; HW adds lane*16

  auto stage = [&](int slot, int kt) {
#pragma unroll
    for (int q = 0; q < 4; ++q)
      gload_lds16(gsrc + (size_t)(q * 64) * DIM + kt * 32,
                  smem + slot * 32768 + q * 8192 + dbase);
  };

  stage(0, 0); stage(1, 1);
  asm volatile("s_waitcnt vmcnt(4)" ::: "memory");
  __builtin_amdgcn_s_barrier();
  asm volatile("" ::: "memory");

#pragma unroll
  for (int kt = 0; kt < 16; ++kt) {
    const char* Ab = smem + (kt % 3) * 32768;
    const int fslot = (kt + 2) % 3;
    const int src = (kt + 2 < 16) ? (kt + 2) : 15;  // dummy tail keeps vmcnt uniform
    bf16x8 bfr[4], af[4], af2[4];
#pragma unroll
    for (int j = 0; j < 4; ++j) {
      int r = wc * 64 + j * 16 + lr;
      bfr[j] = *(const bf16x8*)(Ab + r * 128 + (((4 + kc) ^ (r & 7)) << 4));
    }
#pragma unroll
    for (int i = 0; i < 4; ++i) {
      int r = wr * 128 + i * 16 + lr;
      af[i] = *(const bf16x8*)(Ab + r * 128 + ((kc ^ (r & 7)) << 4));
    }
    __builtin_amdgcn_sched_barrier(0);
#pragma unroll
    for (int i = 0; i < 4; ++i) {
      int r = wr * 128 + (i + 4) * 16 + lr;
      af2[i] = *(const bf16x8*)(Ab + r * 128 + ((kc ^ (r & 7)) << 4));
    }
    __builtin_amdgcn_sched_barrier(0);
    stage(fslot, src);
    __builtin_amdgcn_sched_barrier(0);
    __builtin_amdgcn_s_setprio(1);
#pragma unroll
    for (int i = 0; i < 4; ++i)   // compiler emits lgkmcnt(4): af2 still in flight
#pragma unroll
      for (int j = 0; j < 4; ++j)
        acc[i][j] = __builtin_amdgcn_mfma_f32_16x16x32_bf16(af[i], bfr[j], acc[i][j], 0, 0, 0);
    __builtin_amdgcn_s_setprio(0);
    __builtin_amdgcn_sched_barrier(0);
    __builtin_amdgcn_s_setprio(1);
#pragma unroll
    for (int i = 0; i < 4; ++i)   // compiler emits lgkmcnt(0)
#pragma unroll
      for (int j = 0; j < 4; ++j)
        acc[i + 4][j] = __builtin_amdgcn_mfma_f32_16x16x32_bf16(af2[i], bfr[j], acc[i + 4][j], 0, 0, 0);
    __builtin_amdgcn_s_setprio(0);
    __builtin_amdgcn_sched_barrier(0);
    asm volatile("s_waitcnt vmcnt(4)" ::: "memory");
    __builtin_amdgcn_s_barrier();
    asm volatile("" ::: "memory");
  }
}

// ---- 128x128 tile core: 4 waves (2x2), BK=32, 4-slot ring, counted vmcnt(8),
// 1 barrier/tile (R13-verified; best non-qk config). ----
__device__ __forceinline__ void gemm128_core(const unsigned short* __restrict__ gA,
                                             const unsigned short* __restrict__ gB,
                                             char* smem, f32x4 (&acc)[4][4]) {
  const int t = threadIdx.x;  // 0..255
  const int lane = t & 63;
  const int w = t >> 6;
  const int wr = w >> 1, wc = w & 1;
  const int lr = lane & 15, kc = lane >> 4;
  const int ss = (t & 7) ^ ((t >> 3) & 7);
  const unsigned short* gsrc = (ss < 4 ? gA : gB) + (size_t)(t >> 3) * DIM + (ss & 3) * 8;
  const uint32_t dbase = (uint32_t)(t & 192) * 16;

  auto stage = [&](int slot, int kt) {
#pragma unroll
    for (int q = 0; q < 4; ++q)
      gload_lds16(gsrc + (size_t)(q * 32) * DIM + kt * 32,
                  smem + slot * 16384 + q * 4096 + dbase);
  };

  stage(0, 0); stage(1, 1); stage(2, 2);
  asm volatile("s_waitcnt vmcnt(8)" ::: "memory");
  __builtin_amdgcn_s_barrier();
  asm volatile("" ::: "memory");

#pragma unroll
  for (int kt = 0; kt < 16; ++kt) {
    const char* Ab = smem + (kt & 3) * 16384;
    const int fslot = (kt + 3) & 3;
    const int src = (kt + 3 < 16) ? (kt + 3) : 15;
    bf16x8 bfr[4], af[4];
#pragma unroll
    for (int j = 0; j < 4; ++j) {
      int r = wc * 64 + j * 16 + lr;
      bfr[j] = *(const bf16x8*)(Ab + r * 128 + (((4 + kc) ^ (r & 7)) << 4));
    }
#pragma unroll
    for (int i = 0; i < 4; ++i) {
      int r = wr * 64 + i * 16 + lr;
      af[i] = *(const bf16x8*)(Ab + r * 128 + ((kc ^ (r & 7)) << 4));
    }
    __builtin_amdgcn_sched_barrier(0);
    stage(fslot, src);
    __builtin_amdgcn_sched_barrier(0);
    __builtin_amdgcn_s_setprio(1);
#pragma unroll
    for (int i = 0; i < 4; ++i)
#pragma unroll
      for (int j = 0; j < 4; ++j)
        acc[i][j] = __builtin_amdgcn_mfma_f32_16x16x32_bf16(af[i], bfr[j], acc[i][j], 0, 0, 0);
    __builtin_amdgcn_s_setprio(0);
    __builtin_amdgcn_sched_barrier(0);
    asm volatile("s_waitcnt vmcnt(8)" ::: "memory");
    __builtin_amdgcn_s_barrier();
    asm volatile("" ::: "memory");
  }
}

// ---- k_prep: 0-255 gmat 32x32 | 256-287 u | 288-319 wv2 | 320 consts | 321+ R->bf16 ----
__global__ __launch_bounds__(256) void k_prep(
    const float* __restrict__ R, const float* __restrict__ Wq, const float* __restrict__ Wk,
    const float* __restrict__ Wv, const float* __restrict__ bq, const float* __restrict__ bv,
    const float* __restrict__ W1, const float* __restrict__ b1,
    const float* __restrict__ W2, const float* __restrict__ b2,
    unsigned short* __restrict__ Gt, unsigned short* __restrict__ Rb16,
    float* __restrict__ u, float* __restrict__ wv2, float* __restrict__ consts) {
  __shared__ __align__(16) float As[16][34];
  __shared__ __align__(16) float Bs[16][34];
  __shared__ float vecs[512];
  __shared__ float red2[16][17];
  const int bid = blockIdx.x;
  const int t = threadIdx.x;

  if (bid >= 321) {  // R -> bf16 convert only
    size_t base = ((size_t)(bid - 321) * 256 + t) * 8;
    float4 r0 = *(const float4*)&R[base];
    float4 r1 = *(const float4*)&R[base + 4];
    ushort4 lo, hi;
    lo.x = f2bf(r0.x); lo.y = f2bf(r0.y); lo.z = f2bf(r0.z); lo.w = f2bf(r0.w);
    hi.x = f2bf(r1.x); hi.y = f2bf(r1.y); hi.z = f2bf(r1.z); hi.w = f2bf(r1.w);
    *(ushort4*)&Rb16[base] = lo;
    *(ushort4*)&Rb16[base + 4] = hi;
    return;
  }
  if (bid < 256) {  // Gt[q2][q1] = sum_d Wq[d][q1] Wk[d][q2], 32x32 tiles
    int tm = t & 15, tn = t >> 4;
    int q1b = (bid & 15) * 32, q2b = (bid >> 4) * 32;
    int lk = t >> 4, lc = (t & 15) * 2;
    float acc[2][2] = {};
    for (int kb = 0; kb < DIM; kb += 16) {
      *(float2*)&As[lk][lc] = *(const float2*)&Wq[(size_t)(kb + lk) * DIM + q1b + lc];
      *(float2*)&Bs[lk][lc] = *(const float2*)&Wk[(size_t)(kb + lk) * DIM + q2b + lc];
      __syncthreads();
#pragma unroll
      for (int k = 0; k < 16; ++k) {
        float a0 = As[k][tm * 2], a1 = As[k][tm * 2 + 1];
        float b0 = Bs[k][tn * 2], b1v = Bs[k][tn * 2 + 1];
        acc[0][0] = fmaf(a0, b0, acc[0][0]); acc[0][1] = fmaf(a0, b1v, acc[0][1]);
        acc[1][0] = fmaf(a1, b0, acc[1][0]); acc[1][1] = fmaf(a1, b1v, acc[1][1]);
      }
      __syncthreads();
    }
#pragma unroll
    for (int i = 0; i < 2; ++i)
#pragma unroll
      for (int j = 0; j < 2; ++j)
        Gt[(size_t)(q2b + tn * 2 + j) * DIM + (q1b + tm * 2 + i)] = f2bf(acc[i][j]);
    return;
  }
  if (bid < 320) {
    bool isU = bid < 288;
    int qb = (bid - (isU ? 256 : 288)) * 16;
    if (isU) {
      vecs[t] = bq[t];
      vecs[t + 256] = bq[t + 256];
    } else {
      for (int d = t; d < DIM; d += 256) {
        float s = 0.f;
        for (int j = 0; j < HID; ++j) s = fmaf(W2[j], W1[(size_t)j * DIM + d], s);
        vecs[d] = s;
      }
    }
    __syncthreads();
    const float* M = isU ? Wk : Wv;
    int ql = t & 15, ds = t >> 4;
    float s = 0.f;
#pragma unroll 8
    for (int i = 0; i < 32; ++i) {
      int d = ds * 32 + i;
      s = fmaf(vecs[d], M[(size_t)d * DIM + qb + ql], s);
    }
    red2[ds][ql] = s;
    __syncthreads();
    if (t < 16) {
      float r = 0.f;
#pragma unroll
      for (int k = 0; k < 16; ++k) r += red2[k][t];
      (isU ? u : wv2)[qb + t] = r;
    }
    return;
  }
  // bid == 320: const1 = bv.w12 ; c0 = W2.b1 + b2
  {
    for (int d = t; d < DIM; d += 256) {
      float s = 0.f;
      for (int j = 0; j < HID; ++j) s = fmaf(W2[j], W1[(size_t)j * DIM + d], s);
      vecs[d] = s;
    }
    __syncthreads();
    float* red = (float*)red2;
    red[t] = bv[t] * vecs[t] + bv[t + 256] * vecs[t + 256];
    __syncthreads();
    for (int o = 128; o > 0; o >>= 1) {
      if (t < o) red[t] += red[t + o];
      __syncthreads();
    }
    if (t == 0) {
      consts[0] = red[0];
      float s = b2[0];
      for (int j = 0; j < HID; ++j) s = fmaf(W2[j], b1[j], s);
      consts[1] = s;
    }
  }
}

// ---- k_projT: T = Rb16 @ Gt^T + u (128x128 core) with LDS-staged COALESCED C-store;
//      blockIdx.y==0 blocks also compute vw ----
__global__ __launch_bounds__(256, 2) void k_projT(const unsigned short* __restrict__ Rb16,
                                                  const unsigned short* __restrict__ Gt,
                                                  const float* __restrict__ u,
                                                  const float* __restrict__ wv2,
                                                  unsigned short* __restrict__ Tb16,
                                                  float* __restrict__ vw) {
  __shared__ __align__(16) char smem[65536];
  __shared__ float u_lds[128];
  int t = threadIdx.x;
  size_t rowb = (size_t)blockIdx.x * 128;
  int colb = blockIdx.y * 128;
  if (t < 128) u_lds[t] = u[colb + t];
  f32x4 acc[4][4] = {};
  gemm128_core(Rb16 + rowb * DIM, Gt + (size_t)colb * DIM, smem, acc);
  // drain all in-flight (dummy) loads, then reuse smem for the C tile
  asm volatile("s_waitcnt vmcnt(0)" ::: "memory");
  __syncthreads();
  unsigned short* Cs = (unsigned short*)smem;  // [128][136] (pad 8 -> 2-way-free writes)
  const int LDC = 136;
  int lane = t & 63, w = t >> 6, wr = w >> 1, wc = w & 1;
  int lr = lane & 15, kq = lane >> 4;
#pragma unroll
  for (int i = 0; i < 4; ++i)
#pragma unroll
    for (int j = 0; j < 4; ++j)
#pragma unroll
      for (int r = 0; r < 4; ++r) {
        int row = wr * 64 + i * 16 + kq * 4 + r;
        int col = wc * 64 + j * 16 + lr;
        Cs[row * LDC + col] = f2bf(acc[i][j][r] + u_lds[col]);
      }
  __syncthreads();
  // coalesced store: 16-lane groups write 256 contiguous bytes per pass
#pragma unroll
  for (int p = 0; p < 8; ++p) {
    int row = p * 16 + (t >> 4);
    int c0 = (t & 15) * 8;
    u16x8 v = *(const u16x8*)&Cs[row * LDC + c0];  // 272B row stride: 16B-aligned
    *(u16x8*)&Tb16[(rowb + row) * DIM + colb + c0] = v;
  }
  if (blockIdx.y == 0) {  // vw[n] = Rb16[n].wv2 (const1 folded into k_final)
    float* wv2s = (float*)smem;
    __syncthreads();
    if (t < 256) { wv2s[t] = wv2[t]; wv2s[t + 256] = wv2[t + 256]; }
    __syncthreads();
    int row = (int)rowb + (t >> 1);
    const unsigned short* rp = Rb16 + (size_t)row * DIM + (t & 1) * 256;
    const float* wp = wv2s + (t & 1) * 256;
    float s = 0.f;
#pragma unroll 8
    for (int i = 0; i < 32; ++i) {
      bf16x8 v = *(const bf16x8*)(rp + i * 8);
#pragma unroll
      for (int e = 0; e < 8; ++e) s = fmaf(bf2f((unsigned short)v[e]), wp[i * 8 + e], s);
    }
    s += __shfl_xor(s, 1);
    if ((t & 1) == 0) vw[row] = s;
  }
}

// ---- k_qk: S = T @ R^T (256x256 R8 core) + exp + fused s1/den partials ----
__global__ __launch_bounds__(512, 2) void k_qk(const unsigned short* __restrict__ Tb16,
                                               const unsigned short* __restrict__ Rb16,
                                               const float* __restrict__ vw,
                                               float* __restrict__ part_s1,
                                               float* __restrict__ part_den) {
  __shared__ __align__(16) char smem[98304];
  __shared__ float vw_lds[256];
  __shared__ float red_s1[4][256], red_den[4][256];
  int t = threadIdx.x;
  // XCD swizzle: each XCD owns one batch (T+R panels fit its 4MB L2)
  int orig = blockIdx.x;
  int wgid = (orig & 7) * 64 + (orig >> 3);
  int b = wgid >> 6;
  int nb = ((wgid >> 3) & 7) * 256;
  int mb = (wgid & 7) * 256;
  if (t < 256) vw_lds[t] = vw[b * SEQ + mb + t];
  f32x4 acc[8][4] = {};
  gemm256_core(Tb16 + ((size_t)b * SEQ + nb) * DIM,
               Rb16 + ((size_t)b * SEQ + mb) * DIM, smem, acc);
  int lane = t & 63, w = t >> 6, wr = w >> 2, wc = w & 3;
  int lr = lane & 15, kq = lane >> 4;
  const float rs = 0.044194173824159216f;  // 1/sqrt(512)
  float vwl[4];
#pragma unroll
  for (int j = 0; j < 4; ++j) vwl[j] = vw_lds[wc * 64 + j * 16 + lr];
#pragma unroll
  for (int i = 0; i < 8; ++i) {
#pragma unroll
    for (int r = 0; r < 4; ++r) {
      float sa = 0.f, sd = 0.f;
#pragma unroll
      for (int j = 0; j < 4; ++j) {
        float e = __expf(acc[i][j][r] * rs);
        sa = fmaf(e, vwl[j], sa);
        sd += e;
      }
#pragma unroll
      for (int m = 1; m < 16; m <<= 1) { sa += __shfl_xor(sa, m); sd += __shfl_xor(sd, m); }
      if (lr == 0) {
        int rl = wr * 128 + i * 16 + kq * 4 + r;
        red_s1[wc][rl] = sa;
        red_den[wc][rl] = sd;
      }
    }
  }
  __syncthreads();
  if (t < 256) {
    size_t o = ((size_t)b * 8 + (mb >> 8)) * SEQ + nb + t;
    part_s1[o] = red_s1[0][t] + red_s1[1][t] + red_s1[2][t] + red_s1[3][t];
    part_den[o] = red_den[0][t] + red_den[1][t] + red_den[2][t] + red_den[3][t];
  }
}

// ---- k_final: winner = s1/den + const1 + c0 ----
__global__ void k_final(const float* __restrict__ part_s1, const float* __restrict__ part_den,
                        const float* __restrict__ consts, float* __restrict__ out) {
  int n = blockIdx.x * 256 + threadIdx.x;
  int b = n >> 11, nn = n & 2047;
  float s1 = 0.f, dn = 0.f;
#pragma unroll
  for (int i = 0; i < 8; ++i) {
    size_t o = ((size_t)b * 8 + i) * SEQ + nn;
    s1 += part_s1[o];
    dn += part_den[o];
  }
  out[n] = s1 / dn + consts[0] + consts[1];
}

extern "C" void kernel_launch(void* const* d_in, const int* in_sizes, int n_in,
                              void* d_out, int out_size, void* d_ws, size_t ws_size,
                              hipStream_t stream) {
  const float* R  = (const float*)d_in[0];
  const float* Wq = (const float*)d_in[1];
  const float* bq = (const float*)d_in[2];
  const float* Wk = (const float*)d_in[3];
  const float* bk = (const float*)d_in[4];  // cancels in row-softmax
  const float* Wv = (const float*)d_in[5];
  const float* bv = (const float*)d_in[6];
  const float* W1 = (const float*)d_in[7];
  const float* b1 = (const float*)d_in[8];
  const float* W2 = (const float*)d_in[9];
  const float* b2 = (const float*)d_in[10];
  (void)bk;
  float* out = (float*)d_out;

  char* p = (char*)d_ws;
  unsigned short* Rb16 = (unsigned short*)p; p += (size_t)MTOT * DIM * 2;
  unsigned short* Tb16 = (unsigned short*)p; p += (size_t)MTOT * DIM * 2;
  unsigned short* Gt   = (unsigned short*)p; p += (size_t)DIM * DIM * 2;
  float* part_s1  = (float*)p; p += (size_t)BATCH * 8 * SEQ * 4;
  float* part_den = (float*)p; p += (size_t)BATCH * 8 * SEQ * 4;
  float* u      = (float*)p; p += DIM * 4;
  float* wv2    = (float*)p; p += DIM * 4;
  float* vw     = (float*)p; p += MTOT * 4;
  float* consts = (float*)p; p += 16;

  hipLaunchKernelGGL(k_prep, dim3(321 + MTOT * DIM / (256 * 8)), dim3(256), 0, stream,
                     R, Wq, Wk, Wv, bq, bv, W1, b1, W2, b2, Gt, Rb16, u, wv2, consts);
  hipLaunchKernelGGL(k_projT, dim3(MTOT / 128, DIM / 128), dim3(256), 0, stream,
                     Rb16, Gt, u, wv2, Tb16, vw);
  hipLaunchKernelGGL(k_qk, dim3(512), dim3(512), 0, stream, Tb16, Rb16, vw, part_s1, part_den);
  hipLaunchKernelGGL(k_final, dim3(MTOT / 256), dim3(256), 0, stream,
                     part_s1, part_den, consts, out);
}

// Round 17
// 93.067 us; speedup vs baseline: 1.1106x; 1.0286x over previous
//
#include <hip/hip_runtime.h>
#include <math.h>

#define BATCH 8
#define SEQ 2048
#define DIM 512
#define MTOT (BATCH*SEQ)
#define HID 30

typedef short bf16x8 __attribute__((ext_vector_type(8)));
typedef float f32x4 __attribute__((ext_vector_type(4)));

__device__ __forceinline__ unsigned short f2bf(float f) {
  unsigned int u = __float_as_uint(f);
  unsigned int r = (u + 0x7FFFu + ((u >> 16) & 1u)) >> 16;  // RNE
  return (unsigned short)r;
}
__device__ __forceinline__ float bf2f(unsigned short u) {
  return __uint_as_float((unsigned int)u << 16);
}

__device__ __forceinline__ void gload_lds16(const void* g, void* l) {
  __builtin_amdgcn_global_load_lds((const __attribute__((address_space(1))) void*)g,
                                   (__attribute__((address_space(3))) void*)l, 16, 0, 0);
}

// ---- 256x256 tile GEMM core (R8-verified BEST: 67.1 MF/block in ~23.4us): C = A * B^T.
// BK=32, 8 waves (2x4), 3-slot LDS ring, counted vmcnt(4), ONE barrier per K-tile.
// Zero-conflict macro-row layout: row r = 8x16B chunks (A: ss0-3, B: ss4-7),
// physical slot = ss ^ (r&7); staged linearly via global_load_lds, pre-swizzled source.
__device__ __forceinline__ void gemm256_core(const unsigned short* __restrict__ gA,
                                             const unsigned short* __restrict__ gB,
                                             char* smem, f32x4 (&acc)[8][4]) {
  const int t = threadIdx.x;
  const int lane = t & 63;
  const int w = t >> 6;
  const int wr = w >> 2, wc = w & 3;
  const int lr = lane & 15, kc = lane >> 4;
  const int ss = (t & 7) ^ ((t >> 3) & 7);
  const unsigned short* gsrc = (ss < 4 ? gA : gB) + (size_t)(t >> 3) * DIM + (ss & 3) * 8;
  const uint32_t dbase = (uint32_t)(t & 448) * 16;  // wave-uniform base; HW adds lane*16

  auto stage = [&](int slot, int kt) {
#pragma unroll
    for (int q = 0; q < 4; ++q)
      gload_lds16(gsrc + (size_t)(q * 64) * DIM + kt * 32,
                  smem + slot * 32768 + q * 8192 + dbase);
  };

  stage(0, 0); stage(1, 1);
  asm volatile("s_waitcnt vmcnt(4)" ::: "memory");
  __builtin_amdgcn_s_barrier();
  asm volatile("" ::: "memory");

#pragma unroll
  for (int kt = 0; kt < 16; ++kt) {
    const char* Ab = smem + (kt % 3) * 32768;
    const int fslot = (kt + 2) % 3;
    const int src = (kt + 2 < 16) ? (kt + 2) : 15;  // dummy tail keeps vmcnt uniform
    bf16x8 bfr[4], af[4], af2[4];
#pragma unroll
    for (int j = 0; j < 4; ++j) {
      int r = wc * 64 + j * 16 + lr;
      bfr[j] = *(const bf16x8*)(Ab + r * 128 + (((4 + kc) ^ (r & 7)) << 4));
    }
#pragma unroll
    for (int i = 0; i < 4; ++i) {
      int r = wr * 128 + i * 16 + lr;
      af[i] = *(const bf16x8*)(Ab + r * 128 + ((kc ^ (r & 7)) << 4));
    }
    __builtin_amdgcn_sched_barrier(0);
#pragma unroll
    for (int i = 0; i < 4; ++i) {
      int r = wr * 128 + (i + 4) * 16 + lr;
      af2[i] = *(const bf16x8*)(Ab + r * 128 + ((kc ^ (r & 7)) << 4));
    }
    __builtin_amdgcn_sched_barrier(0);
    stage(fslot, src);
    __builtin_amdgcn_sched_barrier(0);
    __builtin_amdgcn_s_setprio(1);
#pragma unroll
    for (int i = 0; i < 4; ++i)   // compiler emits lgkmcnt(4): af2 still in flight
#pragma unroll
      for (int j = 0; j < 4; ++j)
        acc[i][j] = __builtin_amdgcn_mfma_f32_16x16x32_bf16(af[i], bfr[j], acc[i][j], 0, 0, 0);
    __builtin_amdgcn_s_setprio(0);
    __builtin_amdgcn_sched_barrier(0);
    __builtin_amdgcn_s_setprio(1);
#pragma unroll
    for (int i = 0; i < 4; ++i)   // compiler emits lgkmcnt(0)
#pragma unroll
      for (int j = 0; j < 4; ++j)
        acc[i + 4][j] = __builtin_amdgcn_mfma_f32_16x16x32_bf16(af2[i], bfr[j], acc[i + 4][j], 0, 0, 0);
    __builtin_amdgcn_s_setprio(0);
    __builtin_amdgcn_sched_barrier(0);
    asm volatile("s_waitcnt vmcnt(4)" ::: "memory");
    __builtin_amdgcn_s_barrier();
    asm volatile("" ::: "memory");
  }
}

// ---- k_prep: 0-255 gmat 32x32 (reg-dbuf) | 256-287 u | 288-319 wv2 | 320 consts | 321+ R->bf16
__global__ __launch_bounds__(256) void k_prep(
    const float* __restrict__ R, const float* __restrict__ Wq, const float* __restrict__ Wk,
    const float* __restrict__ Wv, const float* __restrict__ bq, const float* __restrict__ bv,
    const float* __restrict__ W1, const float* __restrict__ b1,
    const float* __restrict__ W2, const float* __restrict__ b2,
    unsigned short* __restrict__ Gt, unsigned short* __restrict__ Rb16,
    float* __restrict__ u, float* __restrict__ wv2, float* __restrict__ consts) {
  __shared__ __align__(16) float As[16][34];
  __shared__ __align__(16) float Bs[16][34];
  __shared__ float vecs[512];
  __shared__ float red2[16][17];
  const int bid = blockIdx.x;
  const int t = threadIdx.x;

  if (bid >= 321) {  // R -> bf16 convert only
    size_t base = ((size_t)(bid - 321) * 256 + t) * 8;
    float4 r0 = *(const float4*)&R[base];
    float4 r1 = *(const float4*)&R[base + 4];
    ushort4 lo, hi;
    lo.x = f2bf(r0.x); lo.y = f2bf(r0.y); lo.z = f2bf(r0.z); lo.w = f2bf(r0.w);
    hi.x = f2bf(r1.x); hi.y = f2bf(r1.y); hi.z = f2bf(r1.z); hi.w = f2bf(r1.w);
    *(ushort4*)&Rb16[base] = lo;
    *(ushort4*)&Rb16[base + 4] = hi;
    return;
  }
  if (bid < 256) {  // Gt[q2][q1] = sum_d Wq[d][q1] Wk[d][q2], 32x32 tiles, reg-prefetched
    int tm = t & 15, tn = t >> 4;
    int q1b = (bid & 15) * 32, q2b = (bid >> 4) * 32;
    int lk = t >> 4, lc = (t & 15) * 2;
    float acc[2][2] = {};
    float2 ra = *(const float2*)&Wq[(size_t)lk * DIM + q1b + lc];
    float2 rb = *(const float2*)&Wk[(size_t)lk * DIM + q2b + lc];
    for (int kb = 0; kb < DIM; kb += 16) {
      *(float2*)&As[lk][lc] = ra;
      *(float2*)&Bs[lk][lc] = rb;
      __syncthreads();
      if (kb + 16 < DIM) {
        ra = *(const float2*)&Wq[(size_t)(kb + 16 + lk) * DIM + q1b + lc];
        rb = *(const float2*)&Wk[(size_t)(kb + 16 + lk) * DIM + q2b + lc];
      }
#pragma unroll
      for (int k = 0; k < 16; ++k) {
        float a0 = As[k][tm * 2], a1 = As[k][tm * 2 + 1];
        float b0 = Bs[k][tn * 2], b1v = Bs[k][tn * 2 + 1];
        acc[0][0] = fmaf(a0, b0, acc[0][0]); acc[0][1] = fmaf(a0, b1v, acc[0][1]);
        acc[1][0] = fmaf(a1, b0, acc[1][0]); acc[1][1] = fmaf(a1, b1v, acc[1][1]);
      }
      __syncthreads();
    }
#pragma unroll
    for (int i = 0; i < 2; ++i)
#pragma unroll
      for (int j = 0; j < 2; ++j)
        Gt[(size_t)(q2b + tn * 2 + j) * DIM + (q1b + tm * 2 + i)] = f2bf(acc[i][j]);
    return;
  }
  if (bid < 320) {
    bool isU = bid < 288;
    int qb = (bid - (isU ? 256 : 288)) * 16;
    if (isU) {
      vecs[t] = bq[t];
      vecs[t + 256] = bq[t + 256];
    } else {
      for (int d = t; d < DIM; d += 256) {
        float s = 0.f;
        for (int j = 0; j < HID; ++j) s = fmaf(W2[j], W1[(size_t)j * DIM + d], s);
        vecs[d] = s;
      }
    }
    __syncthreads();
    const float* M = isU ? Wk : Wv;
    int ql = t & 15, ds = t >> 4;
    float s = 0.f;
#pragma unroll 8
    for (int i = 0; i < 32; ++i) {
      int d = ds * 32 + i;
      s = fmaf(vecs[d], M[(size_t)d * DIM + qb + ql], s);
    }
    red2[ds][ql] = s;
    __syncthreads();
    if (t < 16) {
      float r = 0.f;
#pragma unroll
      for (int k = 0; k < 16; ++k) r += red2[k][t];
      (isU ? u : wv2)[qb + t] = r;
    }
    return;
  }
  // bid == 320: const1 = bv.w12 ; c0 = W2.b1 + b2
  {
    for (int d = t; d < DIM; d += 256) {
      float s = 0.f;
      for (int j = 0; j < HID; ++j) s = fmaf(W2[j], W1[(size_t)j * DIM + d], s);
      vecs[d] = s;
    }
    __syncthreads();
    float* red = (float*)red2;
    red[t] = bv[t] * vecs[t] + bv[t + 256] * vecs[t + 256];
    __syncthreads();
    for (int o = 128; o > 0; o >>= 1) {
      if (t < o) red[t] += red[t + o];
      __syncthreads();
    }
    if (t == 0) {
      consts[0] = red[0];
      float s = b2[0];
      for (int j = 0; j < HID; ++j) s = fmaf(W2[j], b1[j], s);
      consts[1] = s;
    }
  }
}

// ---- k_projT: T = Rb16 @ Gt^T + u, using the R8 256x256 core (grid 64x2, 1 round);
//      blockIdx.y==0 blocks also compute vw ----
__global__ __launch_bounds__(512, 2) void k_projT(const unsigned short* __restrict__ Rb16,
                                                  const unsigned short* __restrict__ Gt,
                                                  const float* __restrict__ u,
                                                  const float* __restrict__ wv2,
                                                  unsigned short* __restrict__ Tb16,
                                                  float* __restrict__ vw) {
  __shared__ __align__(16) char smem[98304];
  __shared__ float u_lds[256];
  int t = threadIdx.x;
  size_t rowb = (size_t)blockIdx.x * 256;
  int colb = blockIdx.y * 256;
  if (t < 256) u_lds[t] = u[colb + t];
  f32x4 acc[8][4] = {};
  gemm256_core(Rb16 + rowb * DIM, Gt + (size_t)colb * DIM, smem, acc);
  int lane = t & 63, w = t >> 6, wr = w >> 2, wc = w & 3;
  int lr = lane & 15, kq = lane >> 4;
#pragma unroll
  for (int i = 0; i < 8; ++i)
#pragma unroll
    for (int j = 0; j < 4; ++j)
#pragma unroll
      for (int r = 0; r < 4; ++r) {
        int row = wr * 128 + i * 16 + kq * 4 + r;
        int col = wc * 64 + j * 16 + lr;
        Tb16[(rowb + row) * DIM + colb + col] = f2bf(acc[i][j][r] + u_lds[col]);
      }
  if (blockIdx.y == 0) {  // vw[n] = Rb16[n].wv2 (const1 folded into k_final)
    asm volatile("s_waitcnt vmcnt(0)" ::: "memory");  // retire dummy tail loads
    __syncthreads();
    float* wv2s = (float*)smem;
    wv2s[t] = wv2[t];  // 512 threads cover 512 elems
    __syncthreads();
    int row = (int)rowb + (t >> 1);  // 512 threads -> 256 rows, 2 threads/row
    const unsigned short* rp = Rb16 + (size_t)row * DIM + (t & 1) * 256;
    const float* wp = wv2s + (t & 1) * 256;
    float s = 0.f;
#pragma unroll 8
    for (int i = 0; i < 32; ++i) {
      bf16x8 v = *(const bf16x8*)(rp + i * 8);
#pragma unroll
      for (int e = 0; e < 8; ++e) s = fmaf(bf2f((unsigned short)v[e]), wp[i * 8 + e], s);
    }
    s += __shfl_xor(s, 1);
    if ((t & 1) == 0) vw[row] = s;
  }
}

// ---- k_qk: S = T @ R^T (256x256 R8 core) + exp + fused s1/den partials ----
__global__ __launch_bounds__(512, 2) void k_qk(const unsigned short* __restrict__ Tb16,
                                               const unsigned short* __restrict__ Rb16,
                                               const float* __restrict__ vw,
                                               float* __restrict__ part_s1,
                                               float* __restrict__ part_den) {
  __shared__ __align__(16) char smem[98304];
  __shared__ float vw_lds[256];
  __shared__ float red_s1[4][256], red_den[4][256];
  int t = threadIdx.x;
  // XCD swizzle: each XCD owns one batch (T+R panels fit its 4MB L2)
  int orig = blockIdx.x;
  int wgid = (orig & 7) * 64 + (orig >> 3);
  int b = wgid >> 6;
  int nb = ((wgid >> 3) & 7) * 256;
  int mb = (wgid & 7) * 256;
  if (t < 256) vw_lds[t] = vw[b * SEQ + mb + t];
  f32x4 acc[8][4] = {};
  gemm256_core(Tb16 + ((size_t)b * SEQ + nb) * DIM,
               Rb16 + ((size_t)b * SEQ + mb) * DIM, smem, acc);
  int lane = t & 63, w = t >> 6, wr = w >> 2, wc = w & 3;
  int lr = lane & 15, kq = lane >> 4;
  const float rs = 0.044194173824159216f;  // 1/sqrt(512)
  float vwl[4];
#pragma unroll
  for (int j = 0; j < 4; ++j) vwl[j] = vw_lds[wc * 64 + j * 16 + lr];
#pragma unroll
  for (int i = 0; i < 8; ++i) {
#pragma unroll
    for (int r = 0; r < 4; ++r) {
      float sa = 0.f, sd = 0.f;
#pragma unroll
      for (int j = 0; j < 4; ++j) {
        float e = __expf(acc[i][j][r] * rs);
        sa = fmaf(e, vwl[j], sa);
        sd += e;
      }
#pragma unroll
      for (int m = 1; m < 16; m <<= 1) { sa += __shfl_xor(sa, m); sd += __shfl_xor(sd, m); }
      if (lr == 0) {
        int rl = wr * 128 + i * 16 + kq * 4 + r;
        red_s1[wc][rl] = sa;
        red_den[wc][rl] = sd;
      }
    }
  }
  __syncthreads();
  if (t < 256) {
    size_t o = ((size_t)b * 8 + (mb >> 8)) * SEQ + nb + t;
    part_s1[o] = red_s1[0][t] + red_s1[1][t] + red_s1[2][t] + red_s1[3][t];
    part_den[o] = red_den[0][t] + red_den[1][t] + red_den[2][t] + red_den[3][t];
  }
}

// ---- k_final: winner = s1/den + const1 + c0 ----
__global__ void k_final(const float* __restrict__ part_s1, const float* __restrict__ part_den,
                        const float* __restrict__ consts, float* __restrict__ out) {
  int n = blockIdx.x * 256 + threadIdx.x;
  int b = n >> 11, nn = n & 2047;
  float s1 = 0.f, dn = 0.f;
#pragma unroll
  for (int i = 0; i < 8; ++i) {
    size_t o = ((size_t)b * 8 + i) * SEQ + nn;
    s1 += part_s1[o];
    dn += part_den[o];
  }
  out[n] = s1 / dn + consts[0] + consts[1];
}

extern "C" void kernel_launch(void* const* d_in, const int* in_sizes, int n_in,
                              void* d_out, int out_size, void* d_ws, size_t ws_size,
                              hipStream_t stream) {
  const float* R  = (const float*)d_in[0];
  const float* Wq = (const float*)d_in[1];
  const float* bq = (const float*)d_in[2];
  const float* Wk = (const float*)d_in[3];
  const float* bk = (const float*)d_in[4];  // cancels in row-softmax
  const float* Wv = (const float*)d_in[5];
  const float* bv = (const float*)d_in[6];
  const float* W1 = (const float*)d_in[7];
  const float* b1 = (const float*)d_in[8];
  const float* W2 = (const float*)d_in[9];
  const float* b2 = (const float*)d_in[10];
  (void)bk;
  float* out = (float*)d_out;

  char* p = (char*)d_ws;
  unsigned short* Rb16 = (unsigned short*)p; p += (size_t)MTOT * DIM * 2;
  unsigned short* Tb16 = (unsigned short*)p; p += (size_t)MTOT * DIM * 2;
  unsigned short* Gt   = (unsigned short*)p; p += (size_t)DIM * DIM * 2;
  float* part_s1  = (float*)p; p += (size_t)BATCH * 8 * SEQ * 4;
  float* part_den = (float*)p; p += (size_t)BATCH * 8 * SEQ * 4;
  float* u      = (float*)p; p += DIM * 4;
  float* wv2    = (float*)p; p += DIM * 4;
  float* vw     = (float*)p; p += MTOT * 4;
  float* consts = (float*)p; p += 16;

  hipLaunchKernelGGL(k_prep, dim3(321 + MTOT * DIM / (256 * 8)), dim3(256), 0, stream,
                     R, Wq, Wk, Wv, bq, bv, W1, b1, W2, b2, Gt, Rb16, u, wv2, consts);
  hipLaunchKernelGGL(k_projT, dim3(MTOT / 256, DIM / 256), dim3(512), 0, stream,
                     Rb16, Gt, u, wv2, Tb16, vw);
  hipLaunchKernelGGL(k_qk, dim3(512), dim3(512), 0, stream, Tb16, Rb16, vw, part_s1, part_den);
  hipLaunchKernelGGL(k_final, dim3(MTOT / 256), dim3(256), 0, stream,
                     part_s1, part_den, consts, out);
}

// Round 18
// 91.918 us; speedup vs baseline: 1.1245x; 1.0125x over previous
//
#include <hip/hip_runtime.h>
#include <math.h>

#define BATCH 8
#define SEQ 2048
#define DIM 512
#define MTOT (BATCH*SEQ)
#define HID 30

typedef short bf16x8 __attribute__((ext_vector_type(8)));
typedef float f32x4 __attribute__((ext_vector_type(4)));

__device__ __forceinline__ unsigned short f2bf(float f) {
  unsigned int u = __float_as_uint(f);
  unsigned int r = (u + 0x7FFFu + ((u >> 16) & 1u)) >> 16;  // RNE
  return (unsigned short)r;
}
__device__ __forceinline__ float bf2f(unsigned short u) {
  return __uint_as_float((unsigned int)u << 16);
}

__device__ __forceinline__ void gload_lds16(const void* g, void* l) {
  __builtin_amdgcn_global_load_lds((const __attribute__((address_space(1))) void*)g,
                                   (__attribute__((address_space(3))) void*)l, 16, 0, 0);
}

// ---- 256x256 8-PHASE core (m201 schedule, faithful port): C = A * B^T, K=512 bf16.
// BK=64, 8 waves (2x4), 2 K-tile buffers (buf = kt&1, 64KB each: A 32KB + B 32KB).
// Iteration t: consume tile 2t (phases 0-3), tile 2t+1 (phases 4-7); per phase one
// C-quadrant x K=64 = 16 MFMA between a barrier pair; counted vmcnt(4) at ph3/ph7 only.
// Stage slots from last-read analysis (WAR-safe, >=1 barrier after last read):
//   p0: A(2t+1)->buf1 | p2,p3: B(2t+2)->buf0 | p4: A(2t+2)->buf0 | p6,p7: B(2t+3)->buf1
// FIFO sim: every half-tile vmcnt-retired before first read (prologue 12 loads+vmcnt(4)).
// Layout per matrix region: 256 rows x 128B (8x16B chunks of one BK=64 tile),
// physical chunk = ss ^ (row&7) (R13-verified zero-conflict); linear dest = t*16.
__device__ __forceinline__ void gemm256_8ph(const unsigned short* __restrict__ gA,
                                            const unsigned short* __restrict__ gB,
                                            char* smem, f32x4 (&acc)[8][4]) {
  const int t = threadIdx.x;
  const int lane = t & 63;
  const int w = t >> 6;
  const int wr = w >> 2, wc = w & 3;
  const int lr = lane & 15, kc = lane >> 4;
  const int ss = (t & 7) ^ ((t >> 3) & 7);
  const size_t srcoff = (size_t)(t >> 3) * DIM + ss * 8;
  const uint32_t dst = (uint32_t)t * 16;  // == (t>>3)*128 + (t&7)*16 (linear in half)

  auto stageH = [&](int d, int M, int kt, int h) {  // half-tile: 128 rows, 2 loads/thread
    const unsigned short* g = (M ? gB : gA) + srcoff + ((size_t)h * 128) * DIM + kt * 64;
    char* dest = smem + d * 65536 + M * 32768 + h * 16384 + dst;
    gload_lds16(g, dest);
    gload_lds16(g + (size_t)64 * DIM, dest + 8192);
  };

  // prologue: A(0),B(0)->buf0; B(1)->buf1 (12 loads); retire A(0),B(0)
  stageH(0, 0, 0, 0); stageH(0, 0, 0, 1);
  stageH(0, 1, 0, 0); stageH(0, 1, 0, 1);
  stageH(1, 1, 1, 0); stageH(1, 1, 1, 1);
  asm volatile("s_waitcnt vmcnt(4)" ::: "memory");
  __builtin_amdgcn_s_barrier();
  asm volatile("" ::: "memory");

  bf16x8 bfr[2][4];  // persists across the 4 quadrant phases of a tile
#pragma unroll
  for (int it = 0; it < 4; ++it) {
#pragma unroll
    for (int ph = 0; ph < 8; ++ph) {
      const int d = ph >> 2;   // tile 2it+d lives in buf d
      const int q = ph & 3;    // C-quadrant
      const char* Ab = smem + d * 65536;
      const char* Bb = Ab + 32768;
      bf16x8 af[2][2];
      if (q == 0) {            // 8 bfr reads, once per tile
#pragma unroll
        for (int s = 0; s < 2; ++s)
#pragma unroll
          for (int j = 0; j < 4; ++j) {
            int r = wc * 64 + j * 16 + lr;
            bfr[s][j] = *(const bf16x8*)(Bb + r * 128 + (((s * 4 + kc) ^ (r & 7)) << 4));
          }
      }
#pragma unroll
      for (int i2 = 0; i2 < 2; ++i2)  // 4 af reads
#pragma unroll
        for (int s = 0; s < 2; ++s) {
          int r = wr * 128 + (2 * q + i2) * 16 + lr;
          af[i2][s] = *(const bf16x8*)(Ab + r * 128 + (((s * 4 + kc) ^ (r & 7)) << 4));
        }
      __builtin_amdgcn_sched_barrier(0);
      // stage 1 half-tile (schedule above)
      if (ph == 0) { stageH(1, 0, 2 * it + 1, 0); stageH(1, 0, 2 * it + 1, 1); }
      if (it < 3) {
        if (ph == 2) stageH(0, 1, 2 * it + 2, 0);
        if (ph == 3) stageH(0, 1, 2 * it + 2, 1);
        if (ph == 4) { stageH(0, 0, 2 * it + 2, 0); stageH(0, 0, 2 * it + 2, 1); }
        if (ph == 6) stageH(1, 1, 2 * it + 3, 0);
        if (ph == 7) stageH(1, 1, 2 * it + 3, 1);
      }
      __builtin_amdgcn_sched_barrier(0);
      if (q == 0) asm volatile("s_waitcnt lgkmcnt(8)" ::: "memory");
      __builtin_amdgcn_s_barrier();
      asm volatile("s_waitcnt lgkmcnt(0)" ::: "memory");
      __builtin_amdgcn_sched_barrier(0);
      __builtin_amdgcn_s_setprio(1);
#pragma unroll
      for (int i2 = 0; i2 < 2; ++i2)
#pragma unroll
        for (int s = 0; s < 2; ++s)
#pragma unroll
          for (int j = 0; j < 4; ++j)
            acc[2 * q + i2][j] = __builtin_amdgcn_mfma_f32_16x16x32_bf16(
                af[i2][s], bfr[s][j], acc[2 * q + i2][j], 0, 0, 0);
      __builtin_amdgcn_s_setprio(0);
      __builtin_amdgcn_sched_barrier(0);
      if (ph == 3 || ph == 7)
        asm volatile("s_waitcnt vmcnt(4)" ::: "memory");
      __builtin_amdgcn_s_barrier();
      asm volatile("" ::: "memory");
    }
  }
}

// ---- 256x256 tile GEMM core (R8-verified): used by k_projT ----
__device__ __forceinline__ void gemm256_core(const unsigned short* __restrict__ gA,
                                             const unsigned short* __restrict__ gB,
                                             char* smem, f32x4 (&acc)[8][4]) {
  const int t = threadIdx.x;
  const int lane = t & 63;
  const int w = t >> 6;
  const int wr = w >> 2, wc = w & 3;
  const int lr = lane & 15, kc = lane >> 4;
  const int ss = (t & 7) ^ ((t >> 3) & 7);
  const unsigned short* gsrc = (ss < 4 ? gA : gB) + (size_t)(t >> 3) * DIM + (ss & 3) * 8;
  const uint32_t dbase = (uint32_t)(t & 448) * 16;

  auto stage = [&](int slot, int kt) {
#pragma unroll
    for (int q = 0; q < 4; ++q)
      gload_lds16(gsrc + (size_t)(q * 64) * DIM + kt * 32,
                  smem + slot * 32768 + q * 8192 + dbase);
  };

  stage(0, 0); stage(1, 1);
  asm volatile("s_waitcnt vmcnt(4)" ::: "memory");
  __builtin_amdgcn_s_barrier();
  asm volatile("" ::: "memory");

#pragma unroll
  for (int kt = 0; kt < 16; ++kt) {
    const char* Ab = smem + (kt % 3) * 32768;
    const int fslot = (kt + 2) % 3;
    const int src = (kt + 2 < 16) ? (kt + 2) : 15;
    bf16x8 bfr[4], af[4], af2[4];
#pragma unroll
    for (int j = 0; j < 4; ++j) {
      int r = wc * 64 + j * 16 + lr;
      bfr[j] = *(const bf16x8*)(Ab + r * 128 + (((4 + kc) ^ (r & 7)) << 4));
    }
#pragma unroll
    for (int i = 0; i < 4; ++i) {
      int r = wr * 128 + i * 16 + lr;
      af[i] = *(const bf16x8*)(Ab + r * 128 + ((kc ^ (r & 7)) << 4));
    }
    __builtin_amdgcn_sched_barrier(0);
#pragma unroll
    for (int i = 0; i < 4; ++i) {
      int r = wr * 128 + (i + 4) * 16 + lr;
      af2[i] = *(const bf16x8*)(Ab + r * 128 + ((kc ^ (r & 7)) << 4));
    }
    __builtin_amdgcn_sched_barrier(0);
    stage(fslot, src);
    __builtin_amdgcn_sched_barrier(0);
    __builtin_amdgcn_s_setprio(1);
#pragma unroll
    for (int i = 0; i < 4; ++i)
#pragma unroll
      for (int j = 0; j < 4; ++j)
        acc[i][j] = __builtin_amdgcn_mfma_f32_16x16x32_bf16(af[i], bfr[j], acc[i][j], 0, 0, 0);
    __builtin_amdgcn_s_setprio(0);
    __builtin_amdgcn_sched_barrier(0);
    __builtin_amdgcn_s_setprio(1);
#pragma unroll
    for (int i = 0; i < 4; ++i)
#pragma unroll
      for (int j = 0; j < 4; ++j)
        acc[i + 4][j] = __builtin_amdgcn_mfma_f32_16x16x32_bf16(af2[i], bfr[j], acc[i + 4][j], 0, 0, 0);
    __builtin_amdgcn_s_setprio(0);
    __builtin_amdgcn_sched_barrier(0);
    asm volatile("s_waitcnt vmcnt(4)" ::: "memory");
    __builtin_amdgcn_s_barrier();
    asm volatile("" ::: "memory");
  }
}

// ---- k_prep: 0-255 gmat 32x32 (reg-dbuf) | 256-287 u | 288-319 wv2 | 320 consts | 321+ R->bf16
__global__ __launch_bounds__(256) void k_prep(
    const float* __restrict__ R, const float* __restrict__ Wq, const float* __restrict__ Wk,
    const float* __restrict__ Wv, const float* __restrict__ bq, const float* __restrict__ bv,
    const float* __restrict__ W1, const float* __restrict__ b1,
    const float* __restrict__ W2, const float* __restrict__ b2,
    unsigned short* __restrict__ Gt, unsigned short* __restrict__ Rb16,
    float* __restrict__ u, float* __restrict__ wv2, float* __restrict__ consts) {
  __shared__ __align__(16) float As[16][34];
  __shared__ __align__(16) float Bs[16][34];
  __shared__ float vecs[512];
  __shared__ float red2[16][17];
  const int bid = blockIdx.x;
  const int t = threadIdx.x;

  if (bid >= 321) {  // R -> bf16 convert only
    size_t base = ((size_t)(bid - 321) * 256 + t) * 8;
    float4 r0 = *(const float4*)&R[base];
    float4 r1 = *(const float4*)&R[base + 4];
    ushort4 lo, hi;
    lo.x = f2bf(r0.x); lo.y = f2bf(r0.y); lo.z = f2bf(r0.z); lo.w = f2bf(r0.w);
    hi.x = f2bf(r1.x); hi.y = f2bf(r1.y); hi.z = f2bf(r1.z); hi.w = f2bf(r1.w);
    *(ushort4*)&Rb16[base] = lo;
    *(ushort4*)&Rb16[base + 4] = hi;
    return;
  }
  if (bid < 256) {  // Gt[q2][q1] = sum_d Wq[d][q1] Wk[d][q2], 32x32 tiles, reg-prefetched
    int tm = t & 15, tn = t >> 4;
    int q1b = (bid & 15) * 32, q2b = (bid >> 4) * 32;
    int lk = t >> 4, lc = (t & 15) * 2;
    float acc[2][2] = {};
    float2 ra = *(const float2*)&Wq[(size_t)lk * DIM + q1b + lc];
    float2 rb = *(const float2*)&Wk[(size_t)lk * DIM + q2b + lc];
    for (int kb = 0; kb < DIM; kb += 16) {
      *(float2*)&As[lk][lc] = ra;
      *(float2*)&Bs[lk][lc] = rb;
      __syncthreads();
      if (kb + 16 < DIM) {
        ra = *(const float2*)&Wq[(size_t)(kb + 16 + lk) * DIM + q1b + lc];
        rb = *(const float2*)&Wk[(size_t)(kb + 16 + lk) * DIM + q2b + lc];
      }
#pragma unroll
      for (int k = 0; k < 16; ++k) {
        float a0 = As[k][tm * 2], a1 = As[k][tm * 2 + 1];
        float b0 = Bs[k][tn * 2], b1v = Bs[k][tn * 2 + 1];
        acc[0][0] = fmaf(a0, b0, acc[0][0]); acc[0][1] = fmaf(a0, b1v, acc[0][1]);
        acc[1][0] = fmaf(a1, b0, acc[1][0]); acc[1][1] = fmaf(a1, b1v, acc[1][1]);
      }
      __syncthreads();
    }
#pragma unroll
    for (int i = 0; i < 2; ++i)
#pragma unroll
      for (int j = 0; j < 2; ++j)
        Gt[(size_t)(q2b + tn * 2 + j) * DIM + (q1b + tm * 2 + i)] = f2bf(acc[i][j]);
    return;
  }
  if (bid < 320) {
    bool isU = bid < 288;
    int qb = (bid - (isU ? 256 : 288)) * 16;
    if (isU) {
      vecs[t] = bq[t];
      vecs[t + 256] = bq[t + 256];
    } else {
      for (int d = t; d < DIM; d += 256) {
        float s = 0.f;
        for (int j = 0; j < HID; ++j) s = fmaf(W2[j], W1[(size_t)j * DIM + d], s);
        vecs[d] = s;
      }
    }
    __syncthreads();
    const float* M = isU ? Wk : Wv;
    int ql = t & 15, ds = t >> 4;
    float s = 0.f;
#pragma unroll 8
    for (int i = 0; i < 32; ++i) {
      int d = ds * 32 + i;
      s = fmaf(vecs[d], M[(size_t)d * DIM + qb + ql], s);
    }
    red2[ds][ql] = s;
    __syncthreads();
    if (t < 16) {
      float r = 0.f;
#pragma unroll
      for (int k = 0; k < 16; ++k) r += red2[k][t];
      (isU ? u : wv2)[qb + t] = r;
    }
    return;
  }
  // bid == 320: const1 = bv.w12 ; c0 = W2.b1 + b2
  {
    for (int d = t; d < DIM; d += 256) {
      float s = 0.f;
      for (int j = 0; j < HID; ++j) s = fmaf(W2[j], W1[(size_t)j * DIM + d], s);
      vecs[d] = s;
    }
    __syncthreads();
    float* red = (float*)red2;
    red[t] = bv[t] * vecs[t] + bv[t + 256] * vecs[t + 256];
    __syncthreads();
    for (int o = 128; o > 0; o >>= 1) {
      if (t < o) red[t] += red[t + o];
      __syncthreads();
    }
    if (t == 0) {
      consts[0] = red[0];
      float s = b2[0];
      for (int j = 0; j < HID; ++j) s = fmaf(W2[j], b1[j], s);
      consts[1] = s;
    }
  }
}

// ---- k_projT: T = Rb16 @ Gt^T + u (R8 256x256 core, grid 64x2);
//      blockIdx.y==0 blocks also compute vw ----
__global__ __launch_bounds__(512, 2) void k_projT(const unsigned short* __restrict__ Rb16,
                                                  const unsigned short* __restrict__ Gt,
                                                  const float* __restrict__ u,
                                                  const float* __restrict__ wv2,
                                                  unsigned short* __restrict__ Tb16,
                                                  float* __restrict__ vw) {
  __shared__ __align__(16) char smem[98304];
  __shared__ float u_lds[256];
  int t = threadIdx.x;
  size_t rowb = (size_t)blockIdx.x * 256;
  int colb = blockIdx.y * 256;
  if (t < 256) u_lds[t] = u[colb + t];
  f32x4 acc[8][4] = {};
  gemm256_core(Rb16 + rowb * DIM, Gt + (size_t)colb * DIM, smem, acc);
  int lane = t & 63, w = t >> 6, wr = w >> 2, wc = w & 3;
  int lr = lane & 15, kq = lane >> 4;
#pragma unroll
  for (int i = 0; i < 8; ++i)
#pragma unroll
    for (int j = 0; j < 4; ++j)
#pragma unroll
      for (int r = 0; r < 4; ++r) {
        int row = wr * 128 + i * 16 + kq * 4 + r;
        int col = wc * 64 + j * 16 + lr;
        Tb16[(rowb + row) * DIM + colb + col] = f2bf(acc[i][j][r] + u_lds[col]);
      }
  if (blockIdx.y == 0) {  // vw[n] = Rb16[n].wv2 (const1 folded into k_final)
    asm volatile("s_waitcnt vmcnt(0)" ::: "memory");  // retire dummy tail loads
    __syncthreads();
    float* wv2s = (float*)smem;
    wv2s[t] = wv2[t];
    __syncthreads();
    int row = (int)rowb + (t >> 1);
    const unsigned short* rp = Rb16 + (size_t)row * DIM + (t & 1) * 256;
    const float* wp = wv2s + (t & 1) * 256;
    float s = 0.f;
#pragma unroll 8
    for (int i = 0; i < 32; ++i) {
      bf16x8 v = *(const bf16x8*)(rp + i * 8);
#pragma unroll
      for (int e = 0; e < 8; ++e) s = fmaf(bf2f((unsigned short)v[e]), wp[i * 8 + e], s);
    }
    s += __shfl_xor(s, 1);
    if ((t & 1) == 0) vw[row] = s;
  }
}

// ---- k_qk: S = T @ R^T (8-phase core) + exp + fused s1/den partials ----
__global__ __launch_bounds__(512, 2) void k_qk(const unsigned short* __restrict__ Tb16,
                                               const unsigned short* __restrict__ Rb16,
                                               const float* __restrict__ vw,
                                               float* __restrict__ part_s1,
                                               float* __restrict__ part_den) {
  __shared__ __align__(16) char smem[131072];  // 2 K-tile buffers x (A 32KB + B 32KB)
  __shared__ float vw_lds[256];
  __shared__ float red_s1[4][256], red_den[4][256];
  int t = threadIdx.x;
  // XCD swizzle: each XCD owns one batch (T+R panels fit its 4MB L2)
  int orig = blockIdx.x;
  int wgid = (orig & 7) * 64 + (orig >> 3);
  int b = wgid >> 6;
  int nb = ((wgid >> 3) & 7) * 256;
  int mb = (wgid & 7) * 256;
  if (t < 256) vw_lds[t] = vw[b * SEQ + mb + t];
  f32x4 acc[8][4] = {};
  gemm256_8ph(Tb16 + ((size_t)b * SEQ + nb) * DIM,
              Rb16 + ((size_t)b * SEQ + mb) * DIM, smem, acc);
  int lane = t & 63, w = t >> 6, wr = w >> 2, wc = w & 3;
  int lr = lane & 15, kq = lane >> 4;
  const float rs = 0.044194173824159216f;  // 1/sqrt(512)
  float vwl[4];
#pragma unroll
  for (int j = 0; j < 4; ++j) vwl[j] = vw_lds[wc * 64 + j * 16 + lr];
#pragma unroll
  for (int i = 0; i < 8; ++i) {
#pragma unroll
    for (int r = 0; r < 4; ++r) {
      float sa = 0.f, sd = 0.f;
#pragma unroll
      for (int j = 0; j < 4; ++j) {
        float e = __expf(acc[i][j][r] * rs);
        sa = fmaf(e, vwl[j], sa);
        sd += e;
      }
#pragma unroll
      for (int m = 1; m < 16; m <<= 1) { sa += __shfl_xor(sa, m); sd += __shfl_xor(sd, m); }
      if (lr == 0) {
        int rl = wr * 128 + i * 16 + kq * 4 + r;
        red_s1[wc][rl] = sa;
        red_den[wc][rl] = sd;
      }
    }
  }
  __syncthreads();
  if (t < 256) {
    size_t o = ((size_t)b * 8 + (mb >> 8)) * SEQ + nb + t;
    part_s1[o] = red_s1[0][t] + red_s1[1][t] + red_s1[2][t] + red_s1[3][t];
    part_den[o] = red_den[0][t] + red_den[1][t] + red_den[2][t] + red_den[3][t];
  }
}

// ---- k_final: winner = s1/den + const1 + c0 ----
__global__ void k_final(const float* __restrict__ part_s1, const float* __restrict__ part_den,
                        const float* __restrict__ consts, float* __restrict__ out) {
  int n = blockIdx.x * 256 + threadIdx.x;
  int b = n >> 11, nn = n & 2047;
  float s1 = 0.f, dn = 0.f;
#pragma unroll
  for (int i = 0; i < 8; ++i) {
    size_t o = ((size_t)b * 8 + i) * SEQ + nn;
    s1 += part_s1[o];
    dn += part_den[o];
  }
  out[n] = s1 / dn + consts[0] + consts[1];
}

extern "C" void kernel_launch(void* const* d_in, const int* in_sizes, int n_in,
                              void* d_out, int out_size, void* d_ws, size_t ws_size,
                              hipStream_t stream) {
  const float* R  = (const float*)d_in[0];
  const float* Wq = (const float*)d_in[1];
  const float* bq = (const float*)d_in[2];
  const float* Wk = (const float*)d_in[3];
  const float* bk = (const float*)d_in[4];  // cancels in row-softmax
  const float* Wv = (const float*)d_in[5];
  const float* bv = (const float*)d_in[6];
  const float* W1 = (const float*)d_in[7];
  const float* b1 = (const float*)d_in[8];
  const float* W2 = (const float*)d_in[9];
  const float* b2 = (const float*)d_in[10];
  (void)bk;
  float* out = (float*)d_out;

  char* p = (char*)d_ws;
  unsigned short* Rb16 = (unsigned short*)p; p += (size_t)MTOT * DIM * 2;
  unsigned short* Tb16 = (unsigned short*)p; p += (size_t)MTOT * DIM * 2;
  unsigned short* Gt   = (unsigned short*)p; p += (size_t)DIM * DIM * 2;
  float* part_s1  = (float*)p; p += (size_t)BATCH * 8 * SEQ * 4;
  float* part_den = (float*)p; p += (size_t)BATCH * 8 * SEQ * 4;
  float* u      = (float*)p; p += DIM * 4;
  float* wv2    = (float*)p; p += DIM * 4;
  float* vw     = (float*)p; p += MTOT * 4;
  float* consts = (float*)p; p += 16;

  hipLaunchKernelGGL(k_prep, dim3(321 + MTOT * DIM / (256 * 8)), dim3(256), 0, stream,
                     R, Wq, Wk, Wv, bq, bv, W1, b1, W2, b2, Gt, Rb16, u, wv2, consts);
  hipLaunchKernelGGL(k_projT, dim3(MTOT / 256, DIM / 256), dim3(512), 0, stream,
                     Rb16, Gt, u, wv2, Tb16, vw);
  hipLaunchKernelGGL(k_qk, dim3(512), dim3(512), 0, stream, Tb16, Rb16, vw, part_s1, part_den);
  hipLaunchKernelGGL(k_final, dim3(MTOT / 256), dim3(256), 0, stream,
                     part_s1, part_den, consts, out);
}